// Round 6
// baseline (327.937 us; speedup 1.0000x reference)
//
#include <hip/hip_runtime.h>

// ---------------------------------------------------------------------------
// AttentionActPrune — full MHA forward. B=4, S=2048, H=16, DH=64, D=1024.
// fp32 in/out; threshold 2% of max|ref| -> bf16 MFMA compute.
// Pipeline: cvt_all -> merged QKV GEMM (Q pre-scaled by softmax const; V ->
// Vt[bh][d][s] transposed epilogue) -> flash-attn (32x32 MFMA shapes,
// register P via S^T, block-coop swizzled LDS staging) -> GEMM out (fp32).
// ---------------------------------------------------------------------------

typedef __bf16 bf16;
typedef __bf16 bf16x8 __attribute__((ext_vector_type(8)));
typedef __bf16 bf16x4 __attribute__((ext_vector_type(4)));
typedef short  short4v __attribute__((ext_vector_type(4)));
typedef float  floatx4 __attribute__((ext_vector_type(4)));
typedef float  floatx16 __attribute__((ext_vector_type(16)));

#define NB   4
#define SEQ  2048
#define NH   16
#define DH   64
#define DIM  1024
#define MTOT (NB * SEQ)   // 8192

#define CEXP 0.18033688f   // (1/sqrt(DH)) * log2(e), folded into Q

__device__ __forceinline__ floatx4 zero4() {
    floatx4 z; z[0] = 0.f; z[1] = 0.f; z[2] = 0.f; z[3] = 0.f; return z;
}
__device__ __forceinline__ floatx16 zero16() {
    floatx16 z;
#pragma unroll
    for (int i = 0; i < 16; i++) z[i] = 0.f;
    return z;
}

__device__ __forceinline__ void load_lds16(const bf16* g, bf16* l) {
    __builtin_amdgcn_global_load_lds(
        (__attribute__((address_space(1))) void*)g,
        (__attribute__((address_space(3))) void*)l,
        16, 0, 0);
}

__device__ __forceinline__ short4v pk4(float a, float b, float c, float d) {
    bf16x4 t; t[0] = (bf16)a; t[1] = (bf16)b; t[2] = (bf16)c; t[3] = (bf16)d;
    return __builtin_bit_cast(short4v, t);
}

// ---------------------------------------------------------------------------
// fp32 -> bf16 converts: X (MD elems) then [Wq;Wk;Wv;Wo] (4*DD) in one grid.
// ---------------------------------------------------------------------------
__global__ __launch_bounds__(256) void cvt_all(const float* __restrict__ X,
                                               const float* __restrict__ w0,
                                               const float* __restrict__ w1,
                                               const float* __restrict__ w2,
                                               const float* __restrict__ w3,
                                               bf16* __restrict__ Xb,
                                               bf16* __restrict__ Wb) {
    const size_t MD = (size_t)MTOT * DIM;
    const size_t DD = (size_t)DIM * DIM;   // 2^20
    size_t i = ((size_t)blockIdx.x * 256 + threadIdx.x) * 4;
    float4 f; bf16* dst;
    if (i < MD) {
        f = *(const float4*)(X + i);
        dst = Xb + i;
    } else {
        size_t off = i - MD;
        int w = (int)(off >> 20);
        size_t wi = off & (DD - 1);
        const float* ws = (w == 0) ? w0 : (w == 1) ? w1 : (w == 2) ? w2 : w3;
        f = *(const float4*)(ws + wi);
        dst = Wb + off;
    }
    bf16x4 o;
    o[0] = (bf16)f.x; o[1] = (bf16)f.y; o[2] = (bf16)f.z; o[3] = (bf16)f.w;
    *(bf16x4*)dst = o;
}

// ---------------------------------------------------------------------------
// Merged QKV GEMM. W = [Wq;Wk;Wv;Wo] rows contiguous. blockIdx.x: 0-7 Q,
// 8-15 K, 16-23 V(transposed epilogue). C[m][n]=sum_k A[m][k]W[n][k]+b[n].
// Q output (sel==0) additionally scaled by CEXP (softmax fold).
// ---------------------------------------------------------------------------
__global__ __launch_bounds__(256) void gemm_qkv(const bf16* __restrict__ A,
                                                const bf16* __restrict__ W,
                                                const float* __restrict__ bq,
                                                const float* __restrict__ bk,
                                                const float* __restrict__ bv,
                                                bf16* __restrict__ Qo,
                                                bf16* __restrict__ Ko,
                                                bf16* __restrict__ Vt) {
    __shared__ __align__(16) bf16 As[128 * 32];
    __shared__ __align__(16) bf16 Bs[128 * 32];
    __shared__ __align__(16) bf16 Ts[64 * 136];

    const int tid  = threadIdx.x;
    const int wave = tid >> 6, lane = tid & 63;
    const int quad = lane >> 4, l16 = lane & 15;
    const int sel = blockIdx.x >> 3;            // 0=Q 1=K 2=V
    const int nt  = blockIdx.x & 7;
    const int m0 = blockIdx.y * 128, n0 = nt * 128;
    const int wm = (wave & 1) * 64, wn = (wave >> 1) * 64;
    const bf16* Wsel = W + (size_t)(sel * DIM + n0) * DIM;
    const float* bias = (sel == 0) ? bq : (sel == 1) ? bk : bv;
    const float scale = (sel == 0) ? CEXP : 1.0f;

    floatx4 acc[4][4];
#pragma unroll
    for (int mi = 0; mi < 4; mi++)
#pragma unroll
        for (int ni = 0; ni < 4; ni++) acc[mi][ni] = zero4();

    for (int k0 = 0; k0 < DIM; k0 += 32) {
        __syncthreads();
#pragma unroll
        for (int i = 0; i < 2; i++) {
            const int cb = wave * 128 + i * 64;
            const int c  = cb + lane;
            const int row = c >> 2;
            const int kc  = (c & 3) * 8;
            load_lds16(A + (size_t)(m0 + row) * DIM + k0 + kc, &As[cb * 8]);
            load_lds16(Wsel + (size_t)row * DIM + k0 + kc, &Bs[cb * 8]);
        }
        __syncthreads();

        bf16x8 af[4], bfr[4];
#pragma unroll
        for (int mi = 0; mi < 4; mi++)
            af[mi] = *(const bf16x8*)&As[(wm + mi * 16 + l16) * 32 + quad * 8];
#pragma unroll
        for (int ni = 0; ni < 4; ni++)
            bfr[ni] = *(const bf16x8*)&Bs[(wn + ni * 16 + l16) * 32 + quad * 8];
#pragma unroll
        for (int mi = 0; mi < 4; mi++)
#pragma unroll
            for (int ni = 0; ni < 4; ni++)
                acc[mi][ni] = __builtin_amdgcn_mfma_f32_16x16x32_bf16(
                    af[mi], bfr[ni], acc[mi][ni], 0, 0, 0);
    }

    if (sel < 2) {
        bf16* C = (sel == 0) ? Qo : Ko;
#pragma unroll
        for (int mi = 0; mi < 4; mi++) {
            const int rbase = m0 + wm + mi * 16 + quad * 4;
#pragma unroll
            for (int ni = 0; ni < 4; ni++) {
                const int col = n0 + wn + ni * 16 + l16;
                const float bval = bias[col];
#pragma unroll
                for (int i = 0; i < 4; i++)
                    C[(size_t)(rbase + i) * DIM + col] =
                        (bf16)((acc[mi][ni][i] + bval) * scale);
            }
        }
    } else {
        // write Vt[(b*NH+h)][d][s], via LDS transpose (two 64-col halves)
        const int b  = blockIdx.y >> 4;
        const int s0 = (blockIdx.y & 15) * 128;
#pragma unroll
        for (int r = 0; r < 2; r++) {
            __syncthreads();
            if ((wave >> 1) == r) {
#pragma unroll
                for (int mi = 0; mi < 4; mi++) {
                    const int m_l = wm + mi * 16 + quad * 4;
#pragma unroll
                    for (int ni = 0; ni < 4; ni++) {
                        const int n_loc = ni * 16 + l16;
                        const float bval = bias[n0 + 64 * r + n_loc];
#pragma unroll
                        for (int i = 0; i < 4; i++)
                            Ts[n_loc * 136 + m_l + i] = (bf16)(acc[mi][ni][i] + bval);
                    }
                }
            }
            __syncthreads();
            const int hh = 2 * nt + r;
            bf16* obase = Vt + ((size_t)(b * NH + hh) * DH) * SEQ + s0;
#pragma unroll
            for (int p = 0; p < 4; p++) {
                const int chunk = p * 256 + tid;
                const int row = chunk >> 4, c0 = (chunk & 15) * 8;
                bf16x8 v = *(const bf16x8*)&Ts[row * 136 + c0];
                *(bf16x8*)(obase + (size_t)row * SEQ + c0) = v;
            }
        }
    }
}

// ---------------------------------------------------------------------------
// Out-projection GEMM (fp32 out)
// ---------------------------------------------------------------------------
__global__ __launch_bounds__(256) void gemm_out(const bf16* __restrict__ A,
                                                const bf16* __restrict__ W,
                                                const float* __restrict__ bias,
                                                float* __restrict__ C) {
    __shared__ __align__(16) bf16 As[128 * 32];
    __shared__ __align__(16) bf16 Bs[128 * 32];

    const int tid  = threadIdx.x;
    const int wave = tid >> 6, lane = tid & 63;
    const int quad = lane >> 4, l16 = lane & 15;
    const int m0 = blockIdx.y * 128, n0 = blockIdx.x * 128;
    const int wm = (wave & 1) * 64, wn = (wave >> 1) * 64;

    floatx4 acc[4][4];
#pragma unroll
    for (int mi = 0; mi < 4; mi++)
#pragma unroll
        for (int ni = 0; ni < 4; ni++) acc[mi][ni] = zero4();

    for (int k0 = 0; k0 < DIM; k0 += 32) {
        __syncthreads();
#pragma unroll
        for (int i = 0; i < 2; i++) {
            const int cb = wave * 128 + i * 64;
            const int c  = cb + lane;
            const int row = c >> 2;
            const int kc  = (c & 3) * 8;
            load_lds16(A + (size_t)(m0 + row) * DIM + k0 + kc, &As[cb * 8]);
            load_lds16(W + (size_t)(n0 + row) * DIM + k0 + kc, &Bs[cb * 8]);
        }
        __syncthreads();

        bf16x8 af[4], bfr[4];
#pragma unroll
        for (int mi = 0; mi < 4; mi++)
            af[mi] = *(const bf16x8*)&As[(wm + mi * 16 + l16) * 32 + quad * 8];
#pragma unroll
        for (int ni = 0; ni < 4; ni++)
            bfr[ni] = *(const bf16x8*)&Bs[(wn + ni * 16 + l16) * 32 + quad * 8];
#pragma unroll
        for (int mi = 0; mi < 4; mi++)
#pragma unroll
            for (int ni = 0; ni < 4; ni++)
                acc[mi][ni] = __builtin_amdgcn_mfma_f32_16x16x32_bf16(
                    af[mi], bfr[ni], acc[mi][ni], 0, 0, 0);
    }

#pragma unroll
    for (int mi = 0; mi < 4; mi++) {
        const int rbase = m0 + wm + mi * 16 + quad * 4;
#pragma unroll
        for (int ni = 0; ni < 4; ni++) {
            const int col = n0 + wn + ni * 16 + l16;
            const float bval = bias[col];
#pragma unroll
            for (int i = 0; i < 4; i++)
                C[(size_t)(rbase + i) * DIM + col] = acc[mi][ni][i] + bval;
        }
    }
}

// ---------------------------------------------------------------------------
// Flash attention, 32x32 MFMA shapes. Block = 2 waves = 64 q rows of one
// (b,h); wave owns 32 q rows. kv tiles of 64 staged in LDS (swizzled 16B
// chunks: row=c>>3, col8=(c&7)^(row&7)).
// S^T via mfma_32x32x16(A=K_rows, B=Q_rows): C-layout col=lane&31=q,
// row=kv=(reg&3)+8*(reg>>2)+4*(lane>>5). Reg group {4r..4r+3} == A-frag
// (k=(lane>>5)*4+j) of mfma_f32_32x32x8bf16_1k covering kv 8r..8r+7 ->
// P never leaves registers. Denominator via ones-B MFMA; its C layout
// matches O's (row=q per reg), so 1/l applies directly at store.
// Q pre-scaled by CEXP so P = exp2(S^T) directly.
// ---------------------------------------------------------------------------
__global__ __launch_bounds__(128, 4) void attn_kernel(const bf16* __restrict__ Q,
                                                      const bf16* __restrict__ K,
                                                      const bf16* __restrict__ Vt,
                                                      bf16* __restrict__ Ctx) {
    __shared__ __align__(16) bf16 Ks[64 * 64];  // swizzled 16B chunks
    __shared__ __align__(16) bf16 Vs[64 * 64];

    const int tid  = threadIdx.x;
    const int wave = tid >> 6, lane = tid & 63;
    const int l32 = lane & 31, lhi = lane >> 5;
    const int bh = blockIdx.x >> 5;         // b*NH + h
    const int qb = blockIdx.x & 31;         // 64-row q block
    const int b  = bh >> 4, h = bh & 15;

    const size_t base_bh = (size_t)b * SEQ * DIM + (size_t)h * DH;
    const size_t base_v  = (size_t)bh * DH * SEQ;
    const bf16* Kg = K + base_bh;
    const bf16* Vg = Vt + base_v;
    const int qt = qb * 64 + wave * 32;     // wave's 32 q rows

    // Q B-frags for QK (32x32x16): B[k=(lane>>5)*8+j][n=q=lane&31], 4 slices
    bf16x8 qf[4];
    {
        const bf16* qp = Q + base_bh + (size_t)(qt + l32) * DIM + lhi * 8;
#pragma unroll
        for (int s = 0; s < 4; s++) qf[s] = *(const bf16x8*)(qp + s * 16);
    }

    // precompute staging rows/cols (4 iters x 64 chunks per array)
    int srow[4], scol8[4];
#pragma unroll
    for (int i = 0; i < 4; i++) {
        const int c = wave * 256 + i * 64 + lane;
        srow[i]  = c >> 3;
        scol8[i] = (c & 7) ^ (srow[i] & 7);
    }

    const short4v ones4 = pk4(1.f, 1.f, 1.f, 1.f);

    floatx16 accO0 = zero16(), accO1 = zero16(), accl = zero16();

    for (int kv0 = 0; kv0 < SEQ; kv0 += 64) {
        __syncthreads();  // readers done with LDS
#pragma unroll
        for (int i = 0; i < 4; i++) {
            const int cb = wave * 256 + i * 64;   // wave-uniform chunk base
            load_lds16(Kg + (size_t)(kv0 + srow[i]) * DIM + scol8[i] * 8,
                       &Ks[cb * 8]);
            load_lds16(Vg + (size_t)srow[i] * SEQ + kv0 + scol8[i] * 8,
                       &Vs[cb * 8]);
        }
        __syncthreads();  // staging visible

#pragma unroll
        for (int kh = 0; kh < 2; kh++) {
            // QK: S^T tile (kv=kh*32.., q=qt..)
            floatx16 st = zero16();
            const int kr = kh * 32 + l32;
#pragma unroll
            for (int s = 0; s < 4; s++) {
                const int c8 = (s * 2 + lhi) ^ (kr & 7);
                const bf16x8 kf = *(const bf16x8*)&Ks[(kr * 8 + c8) * 8];
                st = __builtin_amdgcn_mfma_f32_32x32x16_bf16(kf, qf[s], st, 0, 0, 0);
            }
            // P = exp2(st); reg group r -> A-frag covering kv 8r..8r+7
#pragma unroll
            for (int r = 0; r < 4; r++) {
                const short4v pr = pk4(exp2f(st[4 * r]), exp2f(st[4 * r + 1]),
                                       exp2f(st[4 * r + 2]), exp2f(st[4 * r + 3]));
                // V B-frags: B[k=(lane>>5)*4+j][n=d=lane&31]
                const int kc8a = (kh * 4 + r) ^ (l32 & 7);
                const short4v v0 = __builtin_bit_cast(short4v,
                    *(const bf16x4*)&Vs[(l32 * 8 + kc8a) * 8 + lhi * 4]);
                const int d1 = 32 + l32;
                const int kc8b = (kh * 4 + r) ^ (d1 & 7);
                const short4v v1 = __builtin_bit_cast(short4v,
                    *(const bf16x4*)&Vs[(d1 * 8 + kc8b) * 8 + lhi * 4]);
                accO0 = __builtin_amdgcn_mfma_f32_32x32x8bf16_1k(pr, v0, accO0, 0, 0, 0);
                accO1 = __builtin_amdgcn_mfma_f32_32x32x8bf16_1k(pr, v1, accO1, 0, 0, 0);
                accl  = __builtin_amdgcn_mfma_f32_32x32x8bf16_1k(pr, ones4, accl, 0, 0, 0);
            }
        }
    }

    // store: O row q=(reg&3)+8*(reg>>2)+4*lhi, col d=dh*32+l32
#pragma unroll
    for (int r = 0; r < 16; r++) {
        const int q = qt + (r & 3) + 8 * (r >> 2) + 4 * lhi;
        const float inv = 1.0f / accl[r];
        bf16* cp = Ctx + base_bh + (size_t)q * DIM + l32;
        cp[0]  = (bf16)(accO0[r] * inv);
        cp[32] = (bf16)(accO1[r] * inv);
    }
}

// ---------------------------------------------------------------------------
extern "C" void kernel_launch(void* const* d_in, const int* in_sizes, int n_in,
                              void* d_out, int out_size, void* d_ws, size_t ws_size,
                              hipStream_t stream) {
    const float* X  = (const float*)d_in[0];
    const float* Wq = (const float*)d_in[1];
    const float* bq = (const float*)d_in[2];
    const float* Wk = (const float*)d_in[3];
    const float* bk = (const float*)d_in[4];
    const float* Wv = (const float*)d_in[5];
    const float* bv = (const float*)d_in[6];
    const float* Wo = (const float*)d_in[7];
    const float* bo = (const float*)d_in[8];
    float* out = (float*)d_out;

    const size_t MD = (size_t)MTOT * DIM;
    const size_t DD = (size_t)DIM * DIM;

    bf16* Xb  = (bf16*)d_ws;     // X bf16; reused as ctx after attention
    bf16* Qb  = Xb + MD;
    bf16* Kb  = Qb + MD;
    bf16* Vtb = Kb + MD;         // V transposed [B*H][DH][SEQ]
    bf16* Wqb = Vtb + MD;        // [Wq;Wk;Wv;Wo] rows contiguous
    bf16* Wob = Wqb + 3 * DD;
    if (ws_size < (MD * 4 + DD * 4) * sizeof(bf16)) return;

    cvt_all<<<(int)((MD + 4 * DD) / 4 / 256), 256, 0, stream>>>(
        X, Wq, Wk, Wv, Wo, Xb, Wqb);

    gemm_qkv<<<dim3(24, MTOT / 128), 256, 0, stream>>>(Xb, Wqb, bq, bk, bv,
                                                       Qb, Kb, Vtb);

    // 2048 blocks x 128 threads: 64 (b,h) x 32 q-blocks of 64 rows
    attn_kernel<<<NB * NH * (SEQ / 64), 128, 0, stream>>>(Qb, Kb, Vtb, Xb);

    gemm_out<<<dim3(8, MTOT / 128), 256, 0, stream>>>(Xb, Wob, bo, out);
}

// Round 7
// 312.093 us; speedup vs baseline: 1.0508x; 1.0508x over previous
//
#include <hip/hip_runtime.h>

// ---------------------------------------------------------------------------
// AttentionActPrune — full MHA forward. B=4, S=2048, H=16, DH=64, D=1024.
// fp32 in/out; threshold 2% of max|ref| -> bf16 MFMA compute.
// Pipeline: cvt_all -> merged QKV GEMM (Q pre-scaled by softmax const; V ->
// Vt[bh][d][s] transposed epilogue) -> flash-attn (16x16 shapes, register P
// via S^T, double-buffered swizzled LDS staging, fast exp2) -> GEMM out.
// ---------------------------------------------------------------------------

typedef __bf16 bf16;
typedef __bf16 bf16x8 __attribute__((ext_vector_type(8)));
typedef __bf16 bf16x4 __attribute__((ext_vector_type(4)));
typedef short  short4v __attribute__((ext_vector_type(4)));
typedef float  floatx4 __attribute__((ext_vector_type(4)));

#define NB   4
#define SEQ  2048
#define NH   16
#define DH   64
#define DIM  1024
#define MTOT (NB * SEQ)   // 8192

#define CEXP 0.18033688f   // (1/sqrt(DH)) * log2(e), folded into Q

__device__ __forceinline__ floatx4 zero4() {
    floatx4 z; z[0] = 0.f; z[1] = 0.f; z[2] = 0.f; z[3] = 0.f; return z;
}

__device__ __forceinline__ void load_lds16(const bf16* g, bf16* l) {
    __builtin_amdgcn_global_load_lds(
        (__attribute__((address_space(1))) void*)g,
        (__attribute__((address_space(3))) void*)l,
        16, 0, 0);
}

__device__ __forceinline__ short4v pk4(float a, float b, float c, float d) {
    bf16x4 t; t[0] = (bf16)a; t[1] = (bf16)b; t[2] = (bf16)c; t[3] = (bf16)d;
    return __builtin_bit_cast(short4v, t);
}

// ---------------------------------------------------------------------------
// fp32 -> bf16 converts: X (MD elems) then [Wq;Wk;Wv;Wo] (4*DD) in one grid.
// ---------------------------------------------------------------------------
__global__ __launch_bounds__(256) void cvt_all(const float* __restrict__ X,
                                               const float* __restrict__ w0,
                                               const float* __restrict__ w1,
                                               const float* __restrict__ w2,
                                               const float* __restrict__ w3,
                                               bf16* __restrict__ Xb,
                                               bf16* __restrict__ Wb) {
    const size_t MD = (size_t)MTOT * DIM;
    const size_t DD = (size_t)DIM * DIM;   // 2^20
    size_t i = ((size_t)blockIdx.x * 256 + threadIdx.x) * 4;
    float4 f; bf16* dst;
    if (i < MD) {
        f = *(const float4*)(X + i);
        dst = Xb + i;
    } else {
        size_t off = i - MD;
        int w = (int)(off >> 20);
        size_t wi = off & (DD - 1);
        const float* ws = (w == 0) ? w0 : (w == 1) ? w1 : (w == 2) ? w2 : w3;
        f = *(const float4*)(ws + wi);
        dst = Wb + off;
    }
    bf16x4 o;
    o[0] = (bf16)f.x; o[1] = (bf16)f.y; o[2] = (bf16)f.z; o[3] = (bf16)f.w;
    *(bf16x4*)dst = o;
}

// ---------------------------------------------------------------------------
// Merged QKV GEMM. W = [Wq;Wk;Wv;Wo] rows contiguous. blockIdx.x: 0-7 Q,
// 8-15 K, 16-23 V(transposed epilogue). C[m][n]=sum_k A[m][k]W[n][k]+b[n].
// Q output (sel==0) additionally scaled by CEXP (softmax fold).
// ---------------------------------------------------------------------------
__global__ __launch_bounds__(256) void gemm_qkv(const bf16* __restrict__ A,
                                                const bf16* __restrict__ W,
                                                const float* __restrict__ bq,
                                                const float* __restrict__ bk,
                                                const float* __restrict__ bv,
                                                bf16* __restrict__ Qo,
                                                bf16* __restrict__ Ko,
                                                bf16* __restrict__ Vt) {
    __shared__ __align__(16) bf16 As[128 * 32];
    __shared__ __align__(16) bf16 Bs[128 * 32];
    __shared__ __align__(16) bf16 Ts[64 * 136];

    const int tid  = threadIdx.x;
    const int wave = tid >> 6, lane = tid & 63;
    const int quad = lane >> 4, l16 = lane & 15;
    const int sel = blockIdx.x >> 3;            // 0=Q 1=K 2=V
    const int nt  = blockIdx.x & 7;
    const int m0 = blockIdx.y * 128, n0 = nt * 128;
    const int wm = (wave & 1) * 64, wn = (wave >> 1) * 64;
    const bf16* Wsel = W + (size_t)(sel * DIM + n0) * DIM;
    const float* bias = (sel == 0) ? bq : (sel == 1) ? bk : bv;
    const float scale = (sel == 0) ? CEXP : 1.0f;

    floatx4 acc[4][4];
#pragma unroll
    for (int mi = 0; mi < 4; mi++)
#pragma unroll
        for (int ni = 0; ni < 4; ni++) acc[mi][ni] = zero4();

    for (int k0 = 0; k0 < DIM; k0 += 32) {
        __syncthreads();
#pragma unroll
        for (int i = 0; i < 2; i++) {
            const int cb = wave * 128 + i * 64;
            const int c  = cb + lane;
            const int row = c >> 2;
            const int kc  = (c & 3) * 8;
            load_lds16(A + (size_t)(m0 + row) * DIM + k0 + kc, &As[cb * 8]);
            load_lds16(Wsel + (size_t)row * DIM + k0 + kc, &Bs[cb * 8]);
        }
        __syncthreads();

        bf16x8 af[4], bfr[4];
#pragma unroll
        for (int mi = 0; mi < 4; mi++)
            af[mi] = *(const bf16x8*)&As[(wm + mi * 16 + l16) * 32 + quad * 8];
#pragma unroll
        for (int ni = 0; ni < 4; ni++)
            bfr[ni] = *(const bf16x8*)&Bs[(wn + ni * 16 + l16) * 32 + quad * 8];
#pragma unroll
        for (int mi = 0; mi < 4; mi++)
#pragma unroll
            for (int ni = 0; ni < 4; ni++)
                acc[mi][ni] = __builtin_amdgcn_mfma_f32_16x16x32_bf16(
                    af[mi], bfr[ni], acc[mi][ni], 0, 0, 0);
    }

    if (sel < 2) {
        bf16* C = (sel == 0) ? Qo : Ko;
#pragma unroll
        for (int mi = 0; mi < 4; mi++) {
            const int rbase = m0 + wm + mi * 16 + quad * 4;
#pragma unroll
            for (int ni = 0; ni < 4; ni++) {
                const int col = n0 + wn + ni * 16 + l16;
                const float bval = bias[col];
#pragma unroll
                for (int i = 0; i < 4; i++)
                    C[(size_t)(rbase + i) * DIM + col] =
                        (bf16)((acc[mi][ni][i] + bval) * scale);
            }
        }
    } else {
        // write Vt[(b*NH+h)][d][s], via LDS transpose (two 64-col halves)
        const int b  = blockIdx.y >> 4;
        const int s0 = (blockIdx.y & 15) * 128;
#pragma unroll
        for (int r = 0; r < 2; r++) {
            __syncthreads();
            if ((wave >> 1) == r) {
#pragma unroll
                for (int mi = 0; mi < 4; mi++) {
                    const int m_l = wm + mi * 16 + quad * 4;
#pragma unroll
                    for (int ni = 0; ni < 4; ni++) {
                        const int n_loc = ni * 16 + l16;
                        const float bval = bias[n0 + 64 * r + n_loc];
#pragma unroll
                        for (int i = 0; i < 4; i++)
                            Ts[n_loc * 136 + m_l + i] = (bf16)(acc[mi][ni][i] + bval);
                    }
                }
            }
            __syncthreads();
            const int hh = 2 * nt + r;
            bf16* obase = Vt + ((size_t)(b * NH + hh) * DH) * SEQ + s0;
#pragma unroll
            for (int p = 0; p < 4; p++) {
                const int chunk = p * 256 + tid;
                const int row = chunk >> 4, c0 = (chunk & 15) * 8;
                bf16x8 v = *(const bf16x8*)&Ts[row * 136 + c0];
                *(bf16x8*)(obase + (size_t)row * SEQ + c0) = v;
            }
        }
    }
}

// ---------------------------------------------------------------------------
// Out-projection GEMM (fp32 out)
// ---------------------------------------------------------------------------
__global__ __launch_bounds__(256) void gemm_out(const bf16* __restrict__ A,
                                                const bf16* __restrict__ W,
                                                const float* __restrict__ bias,
                                                float* __restrict__ C) {
    __shared__ __align__(16) bf16 As[128 * 32];
    __shared__ __align__(16) bf16 Bs[128 * 32];

    const int tid  = threadIdx.x;
    const int wave = tid >> 6, lane = tid & 63;
    const int quad = lane >> 4, l16 = lane & 15;
    const int m0 = blockIdx.y * 128, n0 = blockIdx.x * 128;
    const int wm = (wave & 1) * 64, wn = (wave >> 1) * 64;

    floatx4 acc[4][4];
#pragma unroll
    for (int mi = 0; mi < 4; mi++)
#pragma unroll
        for (int ni = 0; ni < 4; ni++) acc[mi][ni] = zero4();

    for (int k0 = 0; k0 < DIM; k0 += 32) {
        __syncthreads();
#pragma unroll
        for (int i = 0; i < 2; i++) {
            const int cb = wave * 128 + i * 64;
            const int c  = cb + lane;
            const int row = c >> 2;
            const int kc  = (c & 3) * 8;
            load_lds16(A + (size_t)(m0 + row) * DIM + k0 + kc, &As[cb * 8]);
            load_lds16(W + (size_t)(n0 + row) * DIM + k0 + kc, &Bs[cb * 8]);
        }
        __syncthreads();

        bf16x8 af[4], bfr[4];
#pragma unroll
        for (int mi = 0; mi < 4; mi++)
            af[mi] = *(const bf16x8*)&As[(wm + mi * 16 + l16) * 32 + quad * 8];
#pragma unroll
        for (int ni = 0; ni < 4; ni++)
            bfr[ni] = *(const bf16x8*)&Bs[(wn + ni * 16 + l16) * 32 + quad * 8];
#pragma unroll
        for (int mi = 0; mi < 4; mi++)
#pragma unroll
            for (int ni = 0; ni < 4; ni++)
                acc[mi][ni] = __builtin_amdgcn_mfma_f32_16x16x32_bf16(
                    af[mi], bfr[ni], acc[mi][ni], 0, 0, 0);
    }

#pragma unroll
    for (int mi = 0; mi < 4; mi++) {
        const int rbase = m0 + wm + mi * 16 + quad * 4;
#pragma unroll
        for (int ni = 0; ni < 4; ni++) {
            const int col = n0 + wn + ni * 16 + l16;
            const float bval = bias[col];
#pragma unroll
            for (int i = 0; i < 4; i++)
                C[(size_t)(rbase + i) * DIM + col] = acc[mi][ni][i] + bval;
        }
    }
}

// ---------------------------------------------------------------------------
// Flash attention, block-cooperative, double-buffered. Block = 4 waves =
// 64 q rows of one (b,h), 16 q rows/wave. kv tiles of 64 staged in
// ping-pong LDS buffers via global_load_lds (16B chunks, XOR swizzle:
// row=c>>3, col8=(c&7)^(row&7)). One barrier per tile: staging for tile
// t+1 is issued right after the barrier, so its latency is covered by
// tile t's compute; the next barrier's vmcnt(0) drain finds it done.
// P stays in registers via the S^T operand-swap trick: S^T C-layout
// (q=l16, kv=quad*4+i) == A-frag of 16x16x16bf16_1k. Q pre-scaled by
// CEXP so P = exp2(z) directly (single v_exp_f32 via builtin).
// ---------------------------------------------------------------------------
__global__ __launch_bounds__(256, 6) void attn_kernel(const bf16* __restrict__ Q,
                                                      const bf16* __restrict__ K,
                                                      const bf16* __restrict__ Vt,
                                                      bf16* __restrict__ Ctx) {
    __shared__ __align__(16) bf16 Ks[2][64 * 64];  // swizzled 16B chunks
    __shared__ __align__(16) bf16 Vs[2][64 * 64];

    const int tid  = threadIdx.x;
    const int wave = tid >> 6, lane = tid & 63;
    const int quad = lane >> 4, l16 = lane & 15;
    const int bh = blockIdx.x >> 5;         // b*NH + h
    const int qb = blockIdx.x & 31;         // 64-row q block
    const int b  = bh >> 4, h = bh & 15;

    const size_t base_bh = (size_t)b * SEQ * DIM + (size_t)h * DH;
    const size_t base_v  = (size_t)bh * DH * SEQ;
    const bf16* Kg = K + base_bh;
    const bf16* Vg = Vt + base_v;
    const int qt = qb * 64 + wave * 16;     // wave's 16 q rows

    // Q frags (B-operand of the swapped QK MFMA): 2 K-halves of DH=64
    const bf16* qp = Q + base_bh + (size_t)(qt + l16) * DIM + quad * 8;
    const bf16x8 aq0 = *(const bf16x8*)qp;
    const bf16x8 aq1 = *(const bf16x8*)(qp + 32);

    // staging addresses (kv-invariant parts)
    const int sc  = wave * 128 + lane;          // chunk id, +64 for i=1
    const int sr0 = sc >> 3,        sr1 = (sc + 64) >> 3;
    const int sc0 = (sc & 7) ^ (sr0 & 7), sc1 = ((sc + 64) & 7) ^ (sr1 & 7);
    const bf16* kga = Kg + (size_t)sr0 * DIM + sc0 * 8;
    const bf16* kgb = Kg + (size_t)sr1 * DIM + sc1 * 8;
    const bf16* vga = Vg + (size_t)sr0 * SEQ + sc0 * 8;
    const bf16* vgb = Vg + (size_t)sr1 * SEQ + sc1 * 8;

    // LDS read offsets (kv-invariant): K frags per t, V frags per t,dt
    int koa[4], kob[4], vo[4][4];
#pragma unroll
    for (int t = 0; t < 4; t++) {
        const int krow = t * 16 + l16;
        koa[t] = (krow * 8 + (quad ^ (krow & 7))) * 8;
        kob[t] = (krow * 8 + ((4 + quad) ^ (krow & 7))) * 8;
#pragma unroll
        for (int dt = 0; dt < 4; dt++) {
            const int d = dt * 16 + l16;
            vo[t][dt] = (d * 8 + ((t * 2 + (quad >> 1)) ^ (d & 7))) * 8
                        + (quad & 1) * 4;
        }
    }

    const short4v ones4 = pk4(1.f, 1.f, 1.f, 1.f);

    floatx4 acc[4], accl = zero4();
#pragma unroll
    for (int dt = 0; dt < 4; dt++) acc[dt] = zero4();

    // prologue: stage tile 0 into buffer 0
    load_lds16(kga, &Ks[0][(wave * 128) * 8]);
    load_lds16(kgb, &Ks[0][(wave * 128 + 64) * 8]);
    load_lds16(vga, &Vs[0][(wave * 128) * 8]);
    load_lds16(vgb, &Vs[0][(wave * 128 + 64) * 8]);

    for (int it = 0; it < SEQ / 64; it++) {
        __syncthreads();  // drains staging issued last iter; readers done
        const int cur = it & 1;
        if (it + 1 < SEQ / 64) {
            const int nxt = cur ^ 1;
            const size_t kvn = (size_t)(it + 1) * 64;
            load_lds16(kga + kvn * DIM, &Ks[nxt][(wave * 128) * 8]);
            load_lds16(kgb + kvn * DIM, &Ks[nxt][(wave * 128 + 64) * 8]);
            load_lds16(vga + kvn, &Vs[nxt][(wave * 128) * 8]);
            load_lds16(vgb + kvn, &Vs[nxt][(wave * 128 + 64) * 8]);
        }

#pragma unroll
        for (int t = 0; t < 4; t++) {
            const bf16x8 kb0 = *(const bf16x8*)&Ks[cur][koa[t]];
            const bf16x8 kb1 = *(const bf16x8*)&Ks[cur][kob[t]];
            short4v vb[4];
#pragma unroll
            for (int dt = 0; dt < 4; dt++)
                vb[dt] = __builtin_bit_cast(short4v,
                    *(const bf16x4*)&Vs[cur][vo[t][dt]]);
            floatx4 z = zero4();
            z = __builtin_amdgcn_mfma_f32_16x16x32_bf16(kb0, aq0, z, 0, 0, 0);
            z = __builtin_amdgcn_mfma_f32_16x16x32_bf16(kb1, aq1, z, 0, 0, 0);
            const short4v p = pk4(__builtin_amdgcn_exp2f(z[0]),
                                  __builtin_amdgcn_exp2f(z[1]),
                                  __builtin_amdgcn_exp2f(z[2]),
                                  __builtin_amdgcn_exp2f(z[3]));
#pragma unroll
            for (int dt = 0; dt < 4; dt++)
                acc[dt] = __builtin_amdgcn_mfma_f32_16x16x16bf16_1k(
                    p, vb[dt], acc[dt], 0, 0, 0);
            accl = __builtin_amdgcn_mfma_f32_16x16x16bf16_1k(
                p, ones4, accl, 0, 0, 0);
        }
    }

    // store: O rows q=qt+quad*4+i, cols dt*16+l16
    float inv[4];
#pragma unroll
    for (int i = 0; i < 4; i++) inv[i] = 1.0f / accl[i];
    bf16* cp = Ctx + base_bh + (size_t)(qt + quad * 4) * DIM + l16;
#pragma unroll
    for (int i = 0; i < 4; i++)
#pragma unroll
        for (int dt = 0; dt < 4; dt++)
            cp[(size_t)i * DIM + dt * 16] = (bf16)(acc[dt][i] * inv[i]);
}

// ---------------------------------------------------------------------------
extern "C" void kernel_launch(void* const* d_in, const int* in_sizes, int n_in,
                              void* d_out, int out_size, void* d_ws, size_t ws_size,
                              hipStream_t stream) {
    const float* X  = (const float*)d_in[0];
    const float* Wq = (const float*)d_in[1];
    const float* bq = (const float*)d_in[2];
    const float* Wk = (const float*)d_in[3];
    const float* bk = (const float*)d_in[4];
    const float* Wv = (const float*)d_in[5];
    const float* bv = (const float*)d_in[6];
    const float* Wo = (const float*)d_in[7];
    const float* bo = (const float*)d_in[8];
    float* out = (float*)d_out;

    const size_t MD = (size_t)MTOT * DIM;
    const size_t DD = (size_t)DIM * DIM;

    bf16* Xb  = (bf16*)d_ws;     // X bf16; reused as ctx after attention
    bf16* Qb  = Xb + MD;
    bf16* Kb  = Qb + MD;
    bf16* Vtb = Kb + MD;         // V transposed [B*H][DH][SEQ]
    bf16* Wqb = Vtb + MD;        // [Wq;Wk;Wv;Wo] rows contiguous
    bf16* Wob = Wqb + 3 * DD;
    if (ws_size < (MD * 4 + DD * 4) * sizeof(bf16)) return;

    cvt_all<<<(int)((MD + 4 * DD) / 4 / 256), 256, 0, stream>>>(
        X, Wq, Wk, Wv, Wo, Xb, Wqb);

    gemm_qkv<<<dim3(24, MTOT / 128), 256, 0, stream>>>(Xb, Wqb, bq, bk, bv,
                                                       Qb, Kb, Vtb);

    // 2048 blocks: 64 (b,h) x 32 q-blocks of 64 rows
    attn_kernel<<<NB * NH * (SEQ / 64), 256, 0, stream>>>(Qb, Kb, Vtb, Xb);

    gemm_out<<<dim3(8, MTOT / 128), 256, 0, stream>>>(Xb, Wob, bo, out);
}

// Round 8
// 311.529 us; speedup vs baseline: 1.0527x; 1.0018x over previous
//
#include <hip/hip_runtime.h>

// ---------------------------------------------------------------------------
// AttentionActPrune — full MHA forward. B=4, S=2048, H=16, DH=64, D=1024.
// fp32 in/out; threshold 2% of max|ref| -> bf16 MFMA compute.
// Pipeline: cvt_all -> merged QKV GEMM (Q pre-scaled by softmax const; V ->
// Vt[bh][d][s] transposed epilogue) -> flash-attn (8-wave blocks, 16x16
// shapes, register P via S^T, double-buffered swizzled LDS staging, fast
// exp2) -> GEMM out (64x128 tiles, fp32).
// ---------------------------------------------------------------------------

typedef __bf16 bf16;
typedef __bf16 bf16x8 __attribute__((ext_vector_type(8)));
typedef __bf16 bf16x4 __attribute__((ext_vector_type(4)));
typedef short  short4v __attribute__((ext_vector_type(4)));
typedef float  floatx4 __attribute__((ext_vector_type(4)));

#define NB   4
#define SEQ  2048
#define NH   16
#define DH   64
#define DIM  1024
#define MTOT (NB * SEQ)   // 8192

#define CEXP 0.18033688f   // (1/sqrt(DH)) * log2(e), folded into Q

__device__ __forceinline__ floatx4 zero4() {
    floatx4 z; z[0] = 0.f; z[1] = 0.f; z[2] = 0.f; z[3] = 0.f; return z;
}

__device__ __forceinline__ void load_lds16(const bf16* g, bf16* l) {
    __builtin_amdgcn_global_load_lds(
        (__attribute__((address_space(1))) void*)g,
        (__attribute__((address_space(3))) void*)l,
        16, 0, 0);
}

__device__ __forceinline__ short4v pk4(float a, float b, float c, float d) {
    bf16x4 t; t[0] = (bf16)a; t[1] = (bf16)b; t[2] = (bf16)c; t[3] = (bf16)d;
    return __builtin_bit_cast(short4v, t);
}

// ---------------------------------------------------------------------------
// fp32 -> bf16 converts: X (MD elems) then [Wq;Wk;Wv;Wo] (4*DD) in one grid.
// ---------------------------------------------------------------------------
__global__ __launch_bounds__(256) void cvt_all(const float* __restrict__ X,
                                               const float* __restrict__ w0,
                                               const float* __restrict__ w1,
                                               const float* __restrict__ w2,
                                               const float* __restrict__ w3,
                                               bf16* __restrict__ Xb,
                                               bf16* __restrict__ Wb) {
    const size_t MD = (size_t)MTOT * DIM;
    const size_t DD = (size_t)DIM * DIM;   // 2^20
    size_t i = ((size_t)blockIdx.x * 256 + threadIdx.x) * 4;
    float4 f; bf16* dst;
    if (i < MD) {
        f = *(const float4*)(X + i);
        dst = Xb + i;
    } else {
        size_t off = i - MD;
        int w = (int)(off >> 20);
        size_t wi = off & (DD - 1);
        const float* ws = (w == 0) ? w0 : (w == 1) ? w1 : (w == 2) ? w2 : w3;
        f = *(const float4*)(ws + wi);
        dst = Wb + off;
    }
    bf16x4 o;
    o[0] = (bf16)f.x; o[1] = (bf16)f.y; o[2] = (bf16)f.z; o[3] = (bf16)f.w;
    *(bf16x4*)dst = o;
}

// ---------------------------------------------------------------------------
// Merged QKV GEMM. W = [Wq;Wk;Wv;Wo] rows contiguous. blockIdx.x: 0-7 Q,
// 8-15 K, 16-23 V(transposed epilogue). C[m][n]=sum_k A[m][k]W[n][k]+b[n].
// Q output (sel==0) additionally scaled by CEXP (softmax fold).
// ---------------------------------------------------------------------------
__global__ __launch_bounds__(256) void gemm_qkv(const bf16* __restrict__ A,
                                                const bf16* __restrict__ W,
                                                const float* __restrict__ bq,
                                                const float* __restrict__ bk,
                                                const float* __restrict__ bv,
                                                bf16* __restrict__ Qo,
                                                bf16* __restrict__ Ko,
                                                bf16* __restrict__ Vt) {
    __shared__ __align__(16) bf16 As[128 * 32];
    __shared__ __align__(16) bf16 Bs[128 * 32];
    __shared__ __align__(16) bf16 Ts[64 * 136];

    const int tid  = threadIdx.x;
    const int wave = tid >> 6, lane = tid & 63;
    const int quad = lane >> 4, l16 = lane & 15;
    const int sel = blockIdx.x >> 3;            // 0=Q 1=K 2=V
    const int nt  = blockIdx.x & 7;
    const int m0 = blockIdx.y * 128, n0 = nt * 128;
    const int wm = (wave & 1) * 64, wn = (wave >> 1) * 64;
    const bf16* Wsel = W + (size_t)(sel * DIM + n0) * DIM;
    const float* bias = (sel == 0) ? bq : (sel == 1) ? bk : bv;
    const float scale = (sel == 0) ? CEXP : 1.0f;

    floatx4 acc[4][4];
#pragma unroll
    for (int mi = 0; mi < 4; mi++)
#pragma unroll
        for (int ni = 0; ni < 4; ni++) acc[mi][ni] = zero4();

    for (int k0 = 0; k0 < DIM; k0 += 32) {
        __syncthreads();
#pragma unroll
        for (int i = 0; i < 2; i++) {
            const int cb = wave * 128 + i * 64;
            const int c  = cb + lane;
            const int row = c >> 2;
            const int kc  = (c & 3) * 8;
            load_lds16(A + (size_t)(m0 + row) * DIM + k0 + kc, &As[cb * 8]);
            load_lds16(Wsel + (size_t)row * DIM + k0 + kc, &Bs[cb * 8]);
        }
        __syncthreads();

        bf16x8 af[4], bfr[4];
#pragma unroll
        for (int mi = 0; mi < 4; mi++)
            af[mi] = *(const bf16x8*)&As[(wm + mi * 16 + l16) * 32 + quad * 8];
#pragma unroll
        for (int ni = 0; ni < 4; ni++)
            bfr[ni] = *(const bf16x8*)&Bs[(wn + ni * 16 + l16) * 32 + quad * 8];
#pragma unroll
        for (int mi = 0; mi < 4; mi++)
#pragma unroll
            for (int ni = 0; ni < 4; ni++)
                acc[mi][ni] = __builtin_amdgcn_mfma_f32_16x16x32_bf16(
                    af[mi], bfr[ni], acc[mi][ni], 0, 0, 0);
    }

    if (sel < 2) {
        bf16* C = (sel == 0) ? Qo : Ko;
#pragma unroll
        for (int mi = 0; mi < 4; mi++) {
            const int rbase = m0 + wm + mi * 16 + quad * 4;
#pragma unroll
            for (int ni = 0; ni < 4; ni++) {
                const int col = n0 + wn + ni * 16 + l16;
                const float bval = bias[col];
#pragma unroll
                for (int i = 0; i < 4; i++)
                    C[(size_t)(rbase + i) * DIM + col] =
                        (bf16)((acc[mi][ni][i] + bval) * scale);
            }
        }
    } else {
        // write Vt[(b*NH+h)][d][s], via LDS transpose (two 64-col halves)
        const int b  = blockIdx.y >> 4;
        const int s0 = (blockIdx.y & 15) * 128;
#pragma unroll
        for (int r = 0; r < 2; r++) {
            __syncthreads();
            if ((wave >> 1) == r) {
#pragma unroll
                for (int mi = 0; mi < 4; mi++) {
                    const int m_l = wm + mi * 16 + quad * 4;
#pragma unroll
                    for (int ni = 0; ni < 4; ni++) {
                        const int n_loc = ni * 16 + l16;
                        const float bval = bias[n0 + 64 * r + n_loc];
#pragma unroll
                        for (int i = 0; i < 4; i++)
                            Ts[n_loc * 136 + m_l + i] = (bf16)(acc[mi][ni][i] + bval);
                    }
                }
            }
            __syncthreads();
            const int hh = 2 * nt + r;
            bf16* obase = Vt + ((size_t)(b * NH + hh) * DH) * SEQ + s0;
#pragma unroll
            for (int p = 0; p < 4; p++) {
                const int chunk = p * 256 + tid;
                const int row = chunk >> 4, c0 = (chunk & 15) * 8;
                bf16x8 v = *(const bf16x8*)&Ts[row * 136 + c0];
                *(bf16x8*)(obase + (size_t)row * SEQ + c0) = v;
            }
        }
    }
}

// ---------------------------------------------------------------------------
// Out-projection GEMM (fp32 out). 64x128 tiles -> 1024 blocks (4/CU).
// ---------------------------------------------------------------------------
__global__ __launch_bounds__(256) void gemm_out(const bf16* __restrict__ A,
                                                const bf16* __restrict__ W,
                                                const float* __restrict__ bias,
                                                float* __restrict__ C) {
    __shared__ __align__(16) bf16 As[64 * 32];
    __shared__ __align__(16) bf16 Bs[128 * 32];

    const int tid  = threadIdx.x;
    const int wave = tid >> 6, lane = tid & 63;
    const int quad = lane >> 4, l16 = lane & 15;
    const int m0 = blockIdx.y * 64, n0 = blockIdx.x * 128;
    const int wm = (wave & 1) * 32, wn = (wave >> 1) * 64;

    floatx4 acc[2][4];
#pragma unroll
    for (int mi = 0; mi < 2; mi++)
#pragma unroll
        for (int ni = 0; ni < 4; ni++) acc[mi][ni] = zero4();

    for (int k0 = 0; k0 < DIM; k0 += 32) {
        __syncthreads();
        {
            // A: 256 chunks, 1 per lane
            const int c  = tid;
            const int row = c >> 2, kc = (c & 3) * 8;
            load_lds16(A + (size_t)(m0 + row) * DIM + k0 + kc,
                       &As[(wave * 64) * 8]);
        }
#pragma unroll
        for (int i = 0; i < 2; i++) {
            // B: 512 chunks, 2 per lane
            const int cb = wave * 128 + i * 64;
            const int c  = cb + lane;
            const int row = c >> 2, kc = (c & 3) * 8;
            load_lds16(W + (size_t)(n0 + row) * DIM + k0 + kc, &Bs[cb * 8]);
        }
        __syncthreads();

        bf16x8 af[2], bfr[4];
#pragma unroll
        for (int mi = 0; mi < 2; mi++)
            af[mi] = *(const bf16x8*)&As[(wm + mi * 16 + l16) * 32 + quad * 8];
#pragma unroll
        for (int ni = 0; ni < 4; ni++)
            bfr[ni] = *(const bf16x8*)&Bs[(wn + ni * 16 + l16) * 32 + quad * 8];
#pragma unroll
        for (int mi = 0; mi < 2; mi++)
#pragma unroll
            for (int ni = 0; ni < 4; ni++)
                acc[mi][ni] = __builtin_amdgcn_mfma_f32_16x16x32_bf16(
                    af[mi], bfr[ni], acc[mi][ni], 0, 0, 0);
    }

#pragma unroll
    for (int mi = 0; mi < 2; mi++) {
        const int rbase = m0 + wm + mi * 16 + quad * 4;
#pragma unroll
        for (int ni = 0; ni < 4; ni++) {
            const int col = n0 + wn + ni * 16 + l16;
            const float bval = bias[col];
#pragma unroll
            for (int i = 0; i < 4; i++)
                C[(size_t)(rbase + i) * DIM + col] = acc[mi][ni][i] + bval;
        }
    }
}

// ---------------------------------------------------------------------------
// Flash attention: 8-wave blocks (512 thr) = 128 q rows of one (b,h),
// 16 q rows/wave. kv tiles of 64 in ping-pong LDS buffers staged by
// global_load_lds (16B chunks, XOR swizzle: row=c>>3, col8=(c&7)^(row&7));
// one chunk per lane per array per tile. One barrier per tile; staging for
// tile t+1 issued right after, covered by tile t's compute. P stays in
// registers via S^T operand swap (C-layout q=l16, kv=quad*4+i == A-frag of
// 16x16x16bf16_1k). Q pre-scaled by CEXP -> P = exp2(z) (one v_exp_f32).
// 4 blocks/CU x 8 waves = 32 waves/CU (full slots); VGPR capped at 64.
// ---------------------------------------------------------------------------
__global__ __launch_bounds__(512, 8) void attn_kernel(const bf16* __restrict__ Q,
                                                      const bf16* __restrict__ K,
                                                      const bf16* __restrict__ Vt,
                                                      bf16* __restrict__ Ctx) {
    __shared__ __align__(16) bf16 Ks[2][64 * 64];  // swizzled 16B chunks
    __shared__ __align__(16) bf16 Vs[2][64 * 64];

    const int tid  = threadIdx.x;
    const int wave = tid >> 6, lane = tid & 63;
    const int quad = lane >> 4, l16 = lane & 15;
    const int bh = blockIdx.x >> 4;         // b*NH + h
    const int qb = blockIdx.x & 15;         // 128-row q block
    const int b  = bh >> 4, h = bh & 15;

    const size_t base_bh = (size_t)b * SEQ * DIM + (size_t)h * DH;
    const size_t base_v  = (size_t)bh * DH * SEQ;
    const int qt = qb * 128 + wave * 16;    // wave's 16 q rows

    // Q frags (B-operand of the swapped QK MFMA): 2 K-halves of DH=64
    const bf16* qp = Q + base_bh + (size_t)(qt + l16) * DIM + quad * 8;
    const bf16x8 aq0 = *(const bf16x8*)qp;
    const bf16x8 aq1 = *(const bf16x8*)(qp + 32);

    // staging: chunk id = tid (512 chunks per array per tile)
    const int sr = tid >> 3;
    const int sc8 = (tid & 7) ^ (sr & 7);
    const bf16* kga = K + base_bh + (size_t)sr * DIM + sc8 * 8;
    const bf16* vga = Vt + base_v + (size_t)sr * SEQ + sc8 * 8;
    const int ldst = (wave * 64) * 8;       // wave-uniform LDS chunk base

    // LDS read offsets (kv-invariant): K frags per t, V frags per t,dt
    int koa[4], kob[4], vo[4][4];
#pragma unroll
    for (int t = 0; t < 4; t++) {
        const int krow = t * 16 + l16;
        koa[t] = (krow * 8 + (quad ^ (krow & 7))) * 8;
        kob[t] = (krow * 8 + ((4 + quad) ^ (krow & 7))) * 8;
#pragma unroll
        for (int dt = 0; dt < 4; dt++) {
            const int d = dt * 16 + l16;
            vo[t][dt] = (d * 8 + ((t * 2 + (quad >> 1)) ^ (d & 7))) * 8
                        + (quad & 1) * 4;
        }
    }

    const short4v ones4 = pk4(1.f, 1.f, 1.f, 1.f);

    floatx4 acc[4], accl = zero4();
#pragma unroll
    for (int dt = 0; dt < 4; dt++) acc[dt] = zero4();

    // prologue: stage tile 0 into buffer 0
    load_lds16(kga, &Ks[0][ldst]);
    load_lds16(vga, &Vs[0][ldst]);

    for (int it = 0; it < SEQ / 64; it++) {
        __syncthreads();  // drains staging issued last iter; readers done
        const int cur = it & 1;
        if (it + 1 < SEQ / 64) {
            const int nxt = cur ^ 1;
            const size_t kvn = (size_t)(it + 1) * 64;
            load_lds16(kga + kvn * DIM, &Ks[nxt][ldst]);
            load_lds16(vga + kvn, &Vs[nxt][ldst]);
        }

#pragma unroll
        for (int t = 0; t < 4; t++) {
            const bf16x8 kb0 = *(const bf16x8*)&Ks[cur][koa[t]];
            const bf16x8 kb1 = *(const bf16x8*)&Ks[cur][kob[t]];
            short4v vb[4];
#pragma unroll
            for (int dt = 0; dt < 4; dt++)
                vb[dt] = __builtin_bit_cast(short4v,
                    *(const bf16x4*)&Vs[cur][vo[t][dt]]);
            floatx4 z = zero4();
            z = __builtin_amdgcn_mfma_f32_16x16x32_bf16(kb0, aq0, z, 0, 0, 0);
            z = __builtin_amdgcn_mfma_f32_16x16x32_bf16(kb1, aq1, z, 0, 0, 0);
            const short4v p = pk4(__builtin_amdgcn_exp2f(z[0]),
                                  __builtin_amdgcn_exp2f(z[1]),
                                  __builtin_amdgcn_exp2f(z[2]),
                                  __builtin_amdgcn_exp2f(z[3]));
#pragma unroll
            for (int dt = 0; dt < 4; dt++)
                acc[dt] = __builtin_amdgcn_mfma_f32_16x16x16bf16_1k(
                    p, vb[dt], acc[dt], 0, 0, 0);
            accl = __builtin_amdgcn_mfma_f32_16x16x16bf16_1k(
                p, ones4, accl, 0, 0, 0);
        }
    }

    // store: O rows q=qt+quad*4+i, cols dt*16+l16
    float inv[4];
#pragma unroll
    for (int i = 0; i < 4; i++) inv[i] = 1.0f / accl[i];
    bf16* cp = Ctx + base_bh + (size_t)(qt + quad * 4) * DIM + l16;
#pragma unroll
    for (int i = 0; i < 4; i++)
#pragma unroll
        for (int dt = 0; dt < 4; dt++)
            cp[(size_t)i * DIM + dt * 16] = (bf16)(acc[dt][i] * inv[i]);
}

// ---------------------------------------------------------------------------
extern "C" void kernel_launch(void* const* d_in, const int* in_sizes, int n_in,
                              void* d_out, int out_size, void* d_ws, size_t ws_size,
                              hipStream_t stream) {
    const float* X  = (const float*)d_in[0];
    const float* Wq = (const float*)d_in[1];
    const float* bq = (const float*)d_in[2];
    const float* Wk = (const float*)d_in[3];
    const float* bk = (const float*)d_in[4];
    const float* Wv = (const float*)d_in[5];
    const float* bv = (const float*)d_in[6];
    const float* Wo = (const float*)d_in[7];
    const float* bo = (const float*)d_in[8];
    float* out = (float*)d_out;

    const size_t MD = (size_t)MTOT * DIM;
    const size_t DD = (size_t)DIM * DIM;

    bf16* Xb  = (bf16*)d_ws;     // X bf16; reused as ctx after attention
    bf16* Qb  = Xb + MD;
    bf16* Kb  = Qb + MD;
    bf16* Vtb = Kb + MD;         // V transposed [B*H][DH][SEQ]
    bf16* Wqb = Vtb + MD;        // [Wq;Wk;Wv;Wo] rows contiguous
    bf16* Wob = Wqb + 3 * DD;
    if (ws_size < (MD * 4 + DD * 4) * sizeof(bf16)) return;

    cvt_all<<<(int)((MD + 4 * DD) / 4 / 256), 256, 0, stream>>>(
        X, Wq, Wk, Wv, Wo, Xb, Wqb);

    gemm_qkv<<<dim3(24, MTOT / 128), 256, 0, stream>>>(Xb, Wqb, bq, bk, bv,
                                                       Qb, Kb, Vtb);

    // 1024 blocks x 512 threads: 64 (b,h) x 16 q-blocks of 128 rows
    attn_kernel<<<NB * NH * (SEQ / 128), 512, 0, stream>>>(Qb, Kb, Vtb, Xb);

    gemm_out<<<dim3(8, MTOT / 64), 256, 0, stream>>>(Xb, Wob, bo, out);
}

// Round 9
// 298.224 us; speedup vs baseline: 1.0996x; 1.0446x over previous
//
#include <hip/hip_runtime.h>

// ---------------------------------------------------------------------------
// AttentionActPrune — full MHA forward. B=4, S=2048, H=16, DH=64, D=1024.
// fp32 in/out; threshold 2% of max|ref| -> bf16 MFMA compute.
// Pipeline: cvt_all -> merged QKV GEMM (Q pre-scaled by softmax const; V ->
// Vt[bh][d][s] transposed epilogue) -> flash-attn (32 q/wave, 4-wave blocks,
// ping-pong swizzled LDS staging, register P via S^T, fast exp2) ->
// GEMM out (128x128, fp32).
// ---------------------------------------------------------------------------

typedef __bf16 bf16;
typedef __bf16 bf16x8 __attribute__((ext_vector_type(8)));
typedef __bf16 bf16x4 __attribute__((ext_vector_type(4)));
typedef short  short4v __attribute__((ext_vector_type(4)));
typedef float  floatx4 __attribute__((ext_vector_type(4)));

#define NB   4
#define SEQ  2048
#define NH   16
#define DH   64
#define DIM  1024
#define MTOT (NB * SEQ)   // 8192

#define CEXP 0.18033688f   // (1/sqrt(DH)) * log2(e), folded into Q

__device__ __forceinline__ floatx4 zero4() {
    floatx4 z; z[0] = 0.f; z[1] = 0.f; z[2] = 0.f; z[3] = 0.f; return z;
}

__device__ __forceinline__ void load_lds16(const bf16* g, bf16* l) {
    __builtin_amdgcn_global_load_lds(
        (__attribute__((address_space(1))) void*)g,
        (__attribute__((address_space(3))) void*)l,
        16, 0, 0);
}

__device__ __forceinline__ short4v pk4(float a, float b, float c, float d) {
    bf16x4 t; t[0] = (bf16)a; t[1] = (bf16)b; t[2] = (bf16)c; t[3] = (bf16)d;
    return __builtin_bit_cast(short4v, t);
}

// ---------------------------------------------------------------------------
// fp32 -> bf16 converts: X (MD elems) then [Wq;Wk;Wv;Wo] (4*DD) in one grid.
// ---------------------------------------------------------------------------
__global__ __launch_bounds__(256) void cvt_all(const float* __restrict__ X,
                                               const float* __restrict__ w0,
                                               const float* __restrict__ w1,
                                               const float* __restrict__ w2,
                                               const float* __restrict__ w3,
                                               bf16* __restrict__ Xb,
                                               bf16* __restrict__ Wb) {
    const size_t MD = (size_t)MTOT * DIM;
    const size_t DD = (size_t)DIM * DIM;   // 2^20
    size_t i = ((size_t)blockIdx.x * 256 + threadIdx.x) * 4;
    float4 f; bf16* dst;
    if (i < MD) {
        f = *(const float4*)(X + i);
        dst = Xb + i;
    } else {
        size_t off = i - MD;
        int w = (int)(off >> 20);
        size_t wi = off & (DD - 1);
        const float* ws = (w == 0) ? w0 : (w == 1) ? w1 : (w == 2) ? w2 : w3;
        f = *(const float4*)(ws + wi);
        dst = Wb + off;
    }
    bf16x4 o;
    o[0] = (bf16)f.x; o[1] = (bf16)f.y; o[2] = (bf16)f.z; o[3] = (bf16)f.w;
    *(bf16x4*)dst = o;
}

// ---------------------------------------------------------------------------
// Merged QKV GEMM. W = [Wq;Wk;Wv;Wo] rows contiguous. blockIdx.x: 0-7 Q,
// 8-15 K, 16-23 V(transposed epilogue). C[m][n]=sum_k A[m][k]W[n][k]+b[n].
// Q output (sel==0) additionally scaled by CEXP (softmax fold).
// ---------------------------------------------------------------------------
__global__ __launch_bounds__(256) void gemm_qkv(const bf16* __restrict__ A,
                                                const bf16* __restrict__ W,
                                                const float* __restrict__ bq,
                                                const float* __restrict__ bk,
                                                const float* __restrict__ bv,
                                                bf16* __restrict__ Qo,
                                                bf16* __restrict__ Ko,
                                                bf16* __restrict__ Vt) {
    __shared__ __align__(16) bf16 As[128 * 32];
    __shared__ __align__(16) bf16 Bs[128 * 32];
    __shared__ __align__(16) bf16 Ts[64 * 136];

    const int tid  = threadIdx.x;
    const int wave = tid >> 6, lane = tid & 63;
    const int quad = lane >> 4, l16 = lane & 15;
    const int sel = blockIdx.x >> 3;            // 0=Q 1=K 2=V
    const int nt  = blockIdx.x & 7;
    const int m0 = blockIdx.y * 128, n0 = nt * 128;
    const int wm = (wave & 1) * 64, wn = (wave >> 1) * 64;
    const bf16* Wsel = W + (size_t)(sel * DIM + n0) * DIM;
    const float* bias = (sel == 0) ? bq : (sel == 1) ? bk : bv;
    const float scale = (sel == 0) ? CEXP : 1.0f;

    floatx4 acc[4][4];
#pragma unroll
    for (int mi = 0; mi < 4; mi++)
#pragma unroll
        for (int ni = 0; ni < 4; ni++) acc[mi][ni] = zero4();

    for (int k0 = 0; k0 < DIM; k0 += 32) {
        __syncthreads();
#pragma unroll
        for (int i = 0; i < 2; i++) {
            const int cb = wave * 128 + i * 64;
            const int c  = cb + lane;
            const int row = c >> 2;
            const int kc  = (c & 3) * 8;
            load_lds16(A + (size_t)(m0 + row) * DIM + k0 + kc, &As[cb * 8]);
            load_lds16(Wsel + (size_t)row * DIM + k0 + kc, &Bs[cb * 8]);
        }
        __syncthreads();

        bf16x8 af[4], bfr[4];
#pragma unroll
        for (int mi = 0; mi < 4; mi++)
            af[mi] = *(const bf16x8*)&As[(wm + mi * 16 + l16) * 32 + quad * 8];
#pragma unroll
        for (int ni = 0; ni < 4; ni++)
            bfr[ni] = *(const bf16x8*)&Bs[(wn + ni * 16 + l16) * 32 + quad * 8];
#pragma unroll
        for (int mi = 0; mi < 4; mi++)
#pragma unroll
            for (int ni = 0; ni < 4; ni++)
                acc[mi][ni] = __builtin_amdgcn_mfma_f32_16x16x32_bf16(
                    af[mi], bfr[ni], acc[mi][ni], 0, 0, 0);
    }

    if (sel < 2) {
        bf16* C = (sel == 0) ? Qo : Ko;
#pragma unroll
        for (int mi = 0; mi < 4; mi++) {
            const int rbase = m0 + wm + mi * 16 + quad * 4;
#pragma unroll
            for (int ni = 0; ni < 4; ni++) {
                const int col = n0 + wn + ni * 16 + l16;
                const float bval = bias[col];
#pragma unroll
                for (int i = 0; i < 4; i++)
                    C[(size_t)(rbase + i) * DIM + col] =
                        (bf16)((acc[mi][ni][i] + bval) * scale);
            }
        }
    } else {
        // write Vt[(b*NH+h)][d][s], via LDS transpose (two 64-col halves)
        const int b  = blockIdx.y >> 4;
        const int s0 = (blockIdx.y & 15) * 128;
#pragma unroll
        for (int r = 0; r < 2; r++) {
            __syncthreads();
            if ((wave >> 1) == r) {
#pragma unroll
                for (int mi = 0; mi < 4; mi++) {
                    const int m_l = wm + mi * 16 + quad * 4;
#pragma unroll
                    for (int ni = 0; ni < 4; ni++) {
                        const int n_loc = ni * 16 + l16;
                        const float bval = bias[n0 + 64 * r + n_loc];
#pragma unroll
                        for (int i = 0; i < 4; i++)
                            Ts[n_loc * 136 + m_l + i] = (bf16)(acc[mi][ni][i] + bval);
                    }
                }
            }
            __syncthreads();
            const int hh = 2 * nt + r;
            bf16* obase = Vt + ((size_t)(b * NH + hh) * DH) * SEQ + s0;
#pragma unroll
            for (int p = 0; p < 4; p++) {
                const int chunk = p * 256 + tid;
                const int row = chunk >> 4, c0 = (chunk & 15) * 8;
                bf16x8 v = *(const bf16x8*)&Ts[row * 136 + c0];
                *(bf16x8*)(obase + (size_t)row * SEQ + c0) = v;
            }
        }
    }
}

// ---------------------------------------------------------------------------
// Out-projection GEMM (fp32 out), 128x128 tiles (reverted: 64-row tiles
// halved MFMA per staged B-byte and cost ~15us).
// ---------------------------------------------------------------------------
__global__ __launch_bounds__(256) void gemm_out(const bf16* __restrict__ A,
                                                const bf16* __restrict__ W,
                                                const float* __restrict__ bias,
                                                float* __restrict__ C) {
    __shared__ __align__(16) bf16 As[128 * 32];
    __shared__ __align__(16) bf16 Bs[128 * 32];

    const int tid  = threadIdx.x;
    const int wave = tid >> 6, lane = tid & 63;
    const int quad = lane >> 4, l16 = lane & 15;
    const int m0 = blockIdx.y * 128, n0 = blockIdx.x * 128;
    const int wm = (wave & 1) * 64, wn = (wave >> 1) * 64;

    floatx4 acc[4][4];
#pragma unroll
    for (int mi = 0; mi < 4; mi++)
#pragma unroll
        for (int ni = 0; ni < 4; ni++) acc[mi][ni] = zero4();

    for (int k0 = 0; k0 < DIM; k0 += 32) {
        __syncthreads();
#pragma unroll
        for (int i = 0; i < 2; i++) {
            const int cb = wave * 128 + i * 64;
            const int c  = cb + lane;
            const int row = c >> 2;
            const int kc  = (c & 3) * 8;
            load_lds16(A + (size_t)(m0 + row) * DIM + k0 + kc, &As[cb * 8]);
            load_lds16(W + (size_t)(n0 + row) * DIM + k0 + kc, &Bs[cb * 8]);
        }
        __syncthreads();

        bf16x8 af[4], bfr[4];
#pragma unroll
        for (int mi = 0; mi < 4; mi++)
            af[mi] = *(const bf16x8*)&As[(wm + mi * 16 + l16) * 32 + quad * 8];
#pragma unroll
        for (int ni = 0; ni < 4; ni++)
            bfr[ni] = *(const bf16x8*)&Bs[(wn + ni * 16 + l16) * 32 + quad * 8];
#pragma unroll
        for (int mi = 0; mi < 4; mi++)
#pragma unroll
            for (int ni = 0; ni < 4; ni++)
                acc[mi][ni] = __builtin_amdgcn_mfma_f32_16x16x32_bf16(
                    af[mi], bfr[ni], acc[mi][ni], 0, 0, 0);
    }

#pragma unroll
    for (int mi = 0; mi < 4; mi++) {
        const int rbase = m0 + wm + mi * 16 + quad * 4;
#pragma unroll
        for (int ni = 0; ni < 4; ni++) {
            const int col = n0 + wn + ni * 16 + l16;
            const float bval = bias[col];
#pragma unroll
            for (int i = 0; i < 4; i++)
                C[(size_t)(rbase + i) * DIM + col] = acc[mi][ni][i] + bval;
        }
    }
}

// ---------------------------------------------------------------------------
// Flash attention: 4-wave blocks (256 thr) = 128 q rows of one (b,h),
// 32 q rows/wave (2 m-subtiles share every K/V LDS fragment read — halves
// LDS bytes/FLOP vs 16q, since the LDS pipe was the round-8 wall).
// kv tiles of 64 in ping-pong LDS buffers staged by global_load_lds
// (16B chunks, XOR swizzle: row=c>>3, col8=(c&7)^(row&7)); 2 chunks per
// lane per array per tile. One barrier per tile; staging for tile t+1
// issued right after it, covered by tile t's compute. P stays in registers
// via S^T operand swap (C-layout q=l16, kv=quad*4+i == A-frag of
// 16x16x16bf16_1k). Q pre-scaled by CEXP -> P = exp2(z) (one v_exp_f32).
// ---------------------------------------------------------------------------
__global__ __launch_bounds__(256, 4) void attn_kernel(const bf16* __restrict__ Q,
                                                      const bf16* __restrict__ K,
                                                      const bf16* __restrict__ Vt,
                                                      bf16* __restrict__ Ctx) {
    __shared__ __align__(16) bf16 Ks[2][64 * 64];  // swizzled 16B chunks
    __shared__ __align__(16) bf16 Vs[2][64 * 64];

    const int tid  = threadIdx.x;
    const int wave = tid >> 6, lane = tid & 63;
    const int quad = lane >> 4, l16 = lane & 15;
    const int bh = blockIdx.x >> 4;         // b*NH + h
    const int qb = blockIdx.x & 15;         // 128-row q block
    const int b  = bh >> 4, h = bh & 15;

    const size_t base_bh = (size_t)b * SEQ * DIM + (size_t)h * DH;
    const size_t base_v  = (size_t)bh * DH * SEQ;
    const int qt = qb * 128 + wave * 32;    // wave's 32 q rows

    // Q frags (B-operand of swapped QK MFMA): 2 m-subtiles x 2 K-halves
    bf16x8 aq[2][2];
#pragma unroll
    for (int m = 0; m < 2; m++) {
        const bf16* qp = Q + base_bh + (size_t)(qt + m * 16 + l16) * DIM + quad * 8;
        aq[m][0] = *(const bf16x8*)qp;
        aq[m][1] = *(const bf16x8*)(qp + 32);
    }

    // staging addresses (kv-invariant): chunk ids sc, sc+64 per array
    const int sc  = wave * 128 + lane;
    const int sr0 = sc >> 3,        sr1 = (sc + 64) >> 3;
    const int sc0 = (sc & 7) ^ (sr0 & 7), sc1 = ((sc + 64) & 7) ^ (sr1 & 7);
    const bf16* kga = K + base_bh + (size_t)sr0 * DIM + sc0 * 8;
    const bf16* kgb = K + base_bh + (size_t)sr1 * DIM + sc1 * 8;
    const bf16* vga = Vt + base_v + (size_t)sr0 * SEQ + sc0 * 8;
    const bf16* vgb = Vt + base_v + (size_t)sr1 * SEQ + sc1 * 8;
    const int ldsa = (wave * 128) * 8, ldsb = (wave * 128 + 64) * 8;

    // LDS read offsets (kv-invariant): K frags per t, V frags per t,dt
    int koa[4], kob[4], vo[4][4];
#pragma unroll
    for (int t = 0; t < 4; t++) {
        const int krow = t * 16 + l16;
        koa[t] = (krow * 8 + (quad ^ (krow & 7))) * 8;
        kob[t] = (krow * 8 + ((4 + quad) ^ (krow & 7))) * 8;
#pragma unroll
        for (int dt = 0; dt < 4; dt++) {
            const int d = dt * 16 + l16;
            vo[t][dt] = (d * 8 + ((t * 2 + (quad >> 1)) ^ (d & 7))) * 8
                        + (quad & 1) * 4;
        }
    }

    const short4v ones4 = pk4(1.f, 1.f, 1.f, 1.f);

    floatx4 acc[2][4], accl[2];
#pragma unroll
    for (int m = 0; m < 2; m++) {
        accl[m] = zero4();
#pragma unroll
        for (int dt = 0; dt < 4; dt++) acc[m][dt] = zero4();
    }

    // prologue: stage tile 0 into buffer 0
    load_lds16(kga, &Ks[0][ldsa]);
    load_lds16(kgb, &Ks[0][ldsb]);
    load_lds16(vga, &Vs[0][ldsa]);
    load_lds16(vgb, &Vs[0][ldsb]);

    for (int it = 0; it < SEQ / 64; it++) {
        __syncthreads();  // drains staging issued last iter; readers done
        const int cur = it & 1;
        if (it + 1 < SEQ / 64) {
            const int nxt = cur ^ 1;
            const size_t kvn = (size_t)(it + 1) * 64;
            load_lds16(kga + kvn * DIM, &Ks[nxt][ldsa]);
            load_lds16(kgb + kvn * DIM, &Ks[nxt][ldsb]);
            load_lds16(vga + kvn, &Vs[nxt][ldsa]);
            load_lds16(vgb + kvn, &Vs[nxt][ldsb]);
        }

#pragma unroll
        for (int t = 0; t < 4; t++) {
            const bf16x8 kb0 = *(const bf16x8*)&Ks[cur][koa[t]];
            const bf16x8 kb1 = *(const bf16x8*)&Ks[cur][kob[t]];
            short4v vb[4];
#pragma unroll
            for (int dt = 0; dt < 4; dt++)
                vb[dt] = __builtin_bit_cast(short4v,
                    *(const bf16x4*)&Vs[cur][vo[t][dt]]);
#pragma unroll
            for (int m = 0; m < 2; m++) {
                floatx4 z = zero4();
                z = __builtin_amdgcn_mfma_f32_16x16x32_bf16(kb0, aq[m][0], z, 0, 0, 0);
                z = __builtin_amdgcn_mfma_f32_16x16x32_bf16(kb1, aq[m][1], z, 0, 0, 0);
                const short4v p = pk4(__builtin_amdgcn_exp2f(z[0]),
                                      __builtin_amdgcn_exp2f(z[1]),
                                      __builtin_amdgcn_exp2f(z[2]),
                                      __builtin_amdgcn_exp2f(z[3]));
#pragma unroll
                for (int dt = 0; dt < 4; dt++)
                    acc[m][dt] = __builtin_amdgcn_mfma_f32_16x16x16bf16_1k(
                        p, vb[dt], acc[m][dt], 0, 0, 0);
                accl[m] = __builtin_amdgcn_mfma_f32_16x16x16bf16_1k(
                    p, ones4, accl[m], 0, 0, 0);
            }
        }
    }

    // store: O rows q=qt+m*16+quad*4+i, cols dt*16+l16
#pragma unroll
    for (int m = 0; m < 2; m++) {
        float inv[4];
#pragma unroll
        for (int i = 0; i < 4; i++) inv[i] = 1.0f / accl[m][i];
        bf16* cp = Ctx + base_bh + (size_t)(qt + m * 16 + quad * 4) * DIM + l16;
#pragma unroll
        for (int i = 0; i < 4; i++)
#pragma unroll
            for (int dt = 0; dt < 4; dt++)
                cp[(size_t)i * DIM + dt * 16] = (bf16)(acc[m][dt][i] * inv[i]);
    }
}

// ---------------------------------------------------------------------------
extern "C" void kernel_launch(void* const* d_in, const int* in_sizes, int n_in,
                              void* d_out, int out_size, void* d_ws, size_t ws_size,
                              hipStream_t stream) {
    const float* X  = (const float*)d_in[0];
    const float* Wq = (const float*)d_in[1];
    const float* bq = (const float*)d_in[2];
    const float* Wk = (const float*)d_in[3];
    const float* bk = (const float*)d_in[4];
    const float* Wv = (const float*)d_in[5];
    const float* bv = (const float*)d_in[6];
    const float* Wo = (const float*)d_in[7];
    const float* bo = (const float*)d_in[8];
    float* out = (float*)d_out;

    const size_t MD = (size_t)MTOT * DIM;
    const size_t DD = (size_t)DIM * DIM;

    bf16* Xb  = (bf16*)d_ws;     // X bf16; reused as ctx after attention
    bf16* Qb  = Xb + MD;
    bf16* Kb  = Qb + MD;
    bf16* Vtb = Kb + MD;         // V transposed [B*H][DH][SEQ]
    bf16* Wqb = Vtb + MD;        // [Wq;Wk;Wv;Wo] rows contiguous
    bf16* Wob = Wqb + 3 * DD;
    if (ws_size < (MD * 4 + DD * 4) * sizeof(bf16)) return;

    cvt_all<<<(int)((MD + 4 * DD) / 4 / 256), 256, 0, stream>>>(
        X, Wq, Wk, Wv, Wo, Xb, Wqb);

    gemm_qkv<<<dim3(24, MTOT / 128), 256, 0, stream>>>(Xb, Wqb, bq, bk, bv,
                                                       Qb, Kb, Vtb);

    // 1024 blocks x 256 threads: 64 (b,h) x 16 q-blocks of 128 rows
    attn_kernel<<<NB * NH * (SEQ / 128), 256, 0, stream>>>(Qb, Kb, Vtb, Xb);

    gemm_out<<<dim3(8, MTOT / 128), 256, 0, stream>>>(Xb, Wob, bo, out);
}

// Round 10
// 294.847 us; speedup vs baseline: 1.1122x; 1.0115x over previous
//
#include <hip/hip_runtime.h>

// ---------------------------------------------------------------------------
// AttentionActPrune — full MHA forward. B=4, S=2048, H=16, DH=64, D=1024.
// fp32 in/out; threshold 2% of max|ref| -> bf16 MFMA compute.
// Pipeline: cvt_all -> merged QKV GEMM (Q pre-scaled by softmax const; V ->
// Vt[bh][d][s] transposed epilogue) -> flash-attn (32 q/wave, 4-wave blocks,
// XCD-swizzled grid for L2 K/V residency, ping-pong swizzled LDS staging,
// register P via S^T, fast exp2) -> GEMM out (128x128, fp32).
// ---------------------------------------------------------------------------

typedef __bf16 bf16;
typedef __bf16 bf16x8 __attribute__((ext_vector_type(8)));
typedef __bf16 bf16x4 __attribute__((ext_vector_type(4)));
typedef short  short4v __attribute__((ext_vector_type(4)));
typedef float  floatx4 __attribute__((ext_vector_type(4)));

#define NB   4
#define SEQ  2048
#define NH   16
#define DH   64
#define DIM  1024
#define MTOT (NB * SEQ)   // 8192

#define CEXP 0.18033688f   // (1/sqrt(DH)) * log2(e), folded into Q

__device__ __forceinline__ floatx4 zero4() {
    floatx4 z; z[0] = 0.f; z[1] = 0.f; z[2] = 0.f; z[3] = 0.f; return z;
}

__device__ __forceinline__ void load_lds16(const bf16* g, bf16* l) {
    __builtin_amdgcn_global_load_lds(
        (__attribute__((address_space(1))) void*)g,
        (__attribute__((address_space(3))) void*)l,
        16, 0, 0);
}

__device__ __forceinline__ short4v pk4(float a, float b, float c, float d) {
    bf16x4 t; t[0] = (bf16)a; t[1] = (bf16)b; t[2] = (bf16)c; t[3] = (bf16)d;
    return __builtin_bit_cast(short4v, t);
}

// ---------------------------------------------------------------------------
// fp32 -> bf16 converts: X (MD elems) then [Wq;Wk;Wv;Wo] (4*DD) in one grid.
// ---------------------------------------------------------------------------
__global__ __launch_bounds__(256) void cvt_all(const float* __restrict__ X,
                                               const float* __restrict__ w0,
                                               const float* __restrict__ w1,
                                               const float* __restrict__ w2,
                                               const float* __restrict__ w3,
                                               bf16* __restrict__ Xb,
                                               bf16* __restrict__ Wb) {
    const size_t MD = (size_t)MTOT * DIM;
    const size_t DD = (size_t)DIM * DIM;   // 2^20
    size_t i = ((size_t)blockIdx.x * 256 + threadIdx.x) * 4;
    float4 f; bf16* dst;
    if (i < MD) {
        f = *(const float4*)(X + i);
        dst = Xb + i;
    } else {
        size_t off = i - MD;
        int w = (int)(off >> 20);
        size_t wi = off & (DD - 1);
        const float* ws = (w == 0) ? w0 : (w == 1) ? w1 : (w == 2) ? w2 : w3;
        f = *(const float4*)(ws + wi);
        dst = Wb + off;
    }
    bf16x4 o;
    o[0] = (bf16)f.x; o[1] = (bf16)f.y; o[2] = (bf16)f.z; o[3] = (bf16)f.w;
    *(bf16x4*)dst = o;
}

// ---------------------------------------------------------------------------
// Merged QKV GEMM. W = [Wq;Wk;Wv;Wo] rows contiguous. blockIdx.x: 0-7 Q,
// 8-15 K, 16-23 V(transposed epilogue). C[m][n]=sum_k A[m][k]W[n][k]+b[n].
// Q output (sel==0) additionally scaled by CEXP (softmax fold).
// ---------------------------------------------------------------------------
__global__ __launch_bounds__(256) void gemm_qkv(const bf16* __restrict__ A,
                                                const bf16* __restrict__ W,
                                                const float* __restrict__ bq,
                                                const float* __restrict__ bk,
                                                const float* __restrict__ bv,
                                                bf16* __restrict__ Qo,
                                                bf16* __restrict__ Ko,
                                                bf16* __restrict__ Vt) {
    __shared__ __align__(16) bf16 As[128 * 32];
    __shared__ __align__(16) bf16 Bs[128 * 32];
    __shared__ __align__(16) bf16 Ts[64 * 136];

    const int tid  = threadIdx.x;
    const int wave = tid >> 6, lane = tid & 63;
    const int quad = lane >> 4, l16 = lane & 15;
    const int sel = blockIdx.x >> 3;            // 0=Q 1=K 2=V
    const int nt  = blockIdx.x & 7;
    const int m0 = blockIdx.y * 128, n0 = nt * 128;
    const int wm = (wave & 1) * 64, wn = (wave >> 1) * 64;
    const bf16* Wsel = W + (size_t)(sel * DIM + n0) * DIM;
    const float* bias = (sel == 0) ? bq : (sel == 1) ? bk : bv;
    const float scale = (sel == 0) ? CEXP : 1.0f;

    floatx4 acc[4][4];
#pragma unroll
    for (int mi = 0; mi < 4; mi++)
#pragma unroll
        for (int ni = 0; ni < 4; ni++) acc[mi][ni] = zero4();

    for (int k0 = 0; k0 < DIM; k0 += 32) {
        __syncthreads();
#pragma unroll
        for (int i = 0; i < 2; i++) {
            const int cb = wave * 128 + i * 64;
            const int c  = cb + lane;
            const int row = c >> 2;
            const int kc  = (c & 3) * 8;
            load_lds16(A + (size_t)(m0 + row) * DIM + k0 + kc, &As[cb * 8]);
            load_lds16(Wsel + (size_t)row * DIM + k0 + kc, &Bs[cb * 8]);
        }
        __syncthreads();

        bf16x8 af[4], bfr[4];
#pragma unroll
        for (int mi = 0; mi < 4; mi++)
            af[mi] = *(const bf16x8*)&As[(wm + mi * 16 + l16) * 32 + quad * 8];
#pragma unroll
        for (int ni = 0; ni < 4; ni++)
            bfr[ni] = *(const bf16x8*)&Bs[(wn + ni * 16 + l16) * 32 + quad * 8];
#pragma unroll
        for (int mi = 0; mi < 4; mi++)
#pragma unroll
            for (int ni = 0; ni < 4; ni++)
                acc[mi][ni] = __builtin_amdgcn_mfma_f32_16x16x32_bf16(
                    af[mi], bfr[ni], acc[mi][ni], 0, 0, 0);
    }

    if (sel < 2) {
        bf16* C = (sel == 0) ? Qo : Ko;
#pragma unroll
        for (int mi = 0; mi < 4; mi++) {
            const int rbase = m0 + wm + mi * 16 + quad * 4;
#pragma unroll
            for (int ni = 0; ni < 4; ni++) {
                const int col = n0 + wn + ni * 16 + l16;
                const float bval = bias[col];
#pragma unroll
                for (int i = 0; i < 4; i++)
                    C[(size_t)(rbase + i) * DIM + col] =
                        (bf16)((acc[mi][ni][i] + bval) * scale);
            }
        }
    } else {
        // write Vt[(b*NH+h)][d][s], via LDS transpose (two 64-col halves)
        const int b  = blockIdx.y >> 4;
        const int s0 = (blockIdx.y & 15) * 128;
#pragma unroll
        for (int r = 0; r < 2; r++) {
            __syncthreads();
            if ((wave >> 1) == r) {
#pragma unroll
                for (int mi = 0; mi < 4; mi++) {
                    const int m_l = wm + mi * 16 + quad * 4;
#pragma unroll
                    for (int ni = 0; ni < 4; ni++) {
                        const int n_loc = ni * 16 + l16;
                        const float bval = bias[n0 + 64 * r + n_loc];
#pragma unroll
                        for (int i = 0; i < 4; i++)
                            Ts[n_loc * 136 + m_l + i] = (bf16)(acc[mi][ni][i] + bval);
                    }
                }
            }
            __syncthreads();
            const int hh = 2 * nt + r;
            bf16* obase = Vt + ((size_t)(b * NH + hh) * DH) * SEQ + s0;
#pragma unroll
            for (int p = 0; p < 4; p++) {
                const int chunk = p * 256 + tid;
                const int row = chunk >> 4, c0 = (chunk & 15) * 8;
                bf16x8 v = *(const bf16x8*)&Ts[row * 136 + c0];
                *(bf16x8*)(obase + (size_t)row * SEQ + c0) = v;
            }
        }
    }
}

// ---------------------------------------------------------------------------
// Out-projection GEMM (fp32 out), 128x128 tiles.
// ---------------------------------------------------------------------------
__global__ __launch_bounds__(256) void gemm_out(const bf16* __restrict__ A,
                                                const bf16* __restrict__ W,
                                                const float* __restrict__ bias,
                                                float* __restrict__ C) {
    __shared__ __align__(16) bf16 As[128 * 32];
    __shared__ __align__(16) bf16 Bs[128 * 32];

    const int tid  = threadIdx.x;
    const int wave = tid >> 6, lane = tid & 63;
    const int quad = lane >> 4, l16 = lane & 15;
    const int m0 = blockIdx.y * 128, n0 = blockIdx.x * 128;
    const int wm = (wave & 1) * 64, wn = (wave >> 1) * 64;

    floatx4 acc[4][4];
#pragma unroll
    for (int mi = 0; mi < 4; mi++)
#pragma unroll
        for (int ni = 0; ni < 4; ni++) acc[mi][ni] = zero4();

    for (int k0 = 0; k0 < DIM; k0 += 32) {
        __syncthreads();
#pragma unroll
        for (int i = 0; i < 2; i++) {
            const int cb = wave * 128 + i * 64;
            const int c  = cb + lane;
            const int row = c >> 2;
            const int kc  = (c & 3) * 8;
            load_lds16(A + (size_t)(m0 + row) * DIM + k0 + kc, &As[cb * 8]);
            load_lds16(W + (size_t)(n0 + row) * DIM + k0 + kc, &Bs[cb * 8]);
        }
        __syncthreads();

        bf16x8 af[4], bfr[4];
#pragma unroll
        for (int mi = 0; mi < 4; mi++)
            af[mi] = *(const bf16x8*)&As[(wm + mi * 16 + l16) * 32 + quad * 8];
#pragma unroll
        for (int ni = 0; ni < 4; ni++)
            bfr[ni] = *(const bf16x8*)&Bs[(wn + ni * 16 + l16) * 32 + quad * 8];
#pragma unroll
        for (int mi = 0; mi < 4; mi++)
#pragma unroll
            for (int ni = 0; ni < 4; ni++)
                acc[mi][ni] = __builtin_amdgcn_mfma_f32_16x16x32_bf16(
                    af[mi], bfr[ni], acc[mi][ni], 0, 0, 0);
    }

#pragma unroll
    for (int mi = 0; mi < 4; mi++) {
        const int rbase = m0 + wm + mi * 16 + quad * 4;
#pragma unroll
        for (int ni = 0; ni < 4; ni++) {
            const int col = n0 + wn + ni * 16 + l16;
            const float bval = bias[col];
#pragma unroll
            for (int i = 0; i < 4; i++)
                C[(size_t)(rbase + i) * DIM + col] = acc[mi][ni][i] + bval;
        }
    }
}

// ---------------------------------------------------------------------------
// Flash attention: 4-wave blocks (256 thr) = 128 q rows of one (b,h),
// 32 q rows/wave. XCD-aware grid swizzle: all 16 q-blocks of one (b,h)
// land on ONE XCD (assuming round-robin blockIdx%8 dispatch), so each
// XCD's concurrent K/V working set is 8 bh x 512 KB = 4 MB ~= its L2 —
// staging loads become L2 hits instead of thrash-misses (round-9 FETCH
// was 139 MB vs 48 MB compulsory). kv tiles of 64 in ping-pong LDS
// buffers via global_load_lds (16B chunks, XOR swizzle). One barrier per
// tile; staging for t+1 issued right after it. P stays in registers via
// S^T operand swap (C-layout q=l16, kv=quad*4+i == A-frag of
// 16x16x16bf16_1k). Q pre-scaled by CEXP -> P = exp2(z).
// ---------------------------------------------------------------------------
__global__ __launch_bounds__(256, 4) void attn_kernel(const bf16* __restrict__ Q,
                                                      const bf16* __restrict__ K,
                                                      const bf16* __restrict__ Vt,
                                                      bf16* __restrict__ Ctx) {
    __shared__ __align__(16) bf16 Ks[2][64 * 64];  // swizzled 16B chunks
    __shared__ __align__(16) bf16 Vs[2][64 * 64];

    const int tid  = threadIdx.x;
    const int wave = tid >> 6, lane = tid & 63;
    const int quad = lane >> 4, l16 = lane & 15;
    // XCD-aware swizzle (1024 blocks, 8 XCDs): xcd gets bh = xcd*8..xcd*8+7
    const int xcd = blockIdx.x & 7;
    const int j   = blockIdx.x >> 3;        // 0..127
    const int bh  = xcd * 8 + (j >> 4);     // b*NH + h
    const int qb  = j & 15;                 // 128-row q block
    const int b   = bh >> 4, h = bh & 15;

    const size_t base_bh = (size_t)b * SEQ * DIM + (size_t)h * DH;
    const size_t base_v  = (size_t)bh * DH * SEQ;
    const int qt = qb * 128 + wave * 32;    // wave's 32 q rows

    // Q frags (B-operand of swapped QK MFMA): 2 m-subtiles x 2 K-halves
    bf16x8 aq[2][2];
#pragma unroll
    for (int m = 0; m < 2; m++) {
        const bf16* qp = Q + base_bh + (size_t)(qt + m * 16 + l16) * DIM + quad * 8;
        aq[m][0] = *(const bf16x8*)qp;
        aq[m][1] = *(const bf16x8*)(qp + 32);
    }

    // staging addresses (kv-invariant): chunk ids sc, sc+64 per array
    const int sc  = wave * 128 + lane;
    const int sr0 = sc >> 3,        sr1 = (sc + 64) >> 3;
    const int sc0 = (sc & 7) ^ (sr0 & 7), sc1 = ((sc + 64) & 7) ^ (sr1 & 7);
    const bf16* kga = K + base_bh + (size_t)sr0 * DIM + sc0 * 8;
    const bf16* kgb = K + base_bh + (size_t)sr1 * DIM + sc1 * 8;
    const bf16* vga = Vt + base_v + (size_t)sr0 * SEQ + sc0 * 8;
    const bf16* vgb = Vt + base_v + (size_t)sr1 * SEQ + sc1 * 8;
    const int ldsa = (wave * 128) * 8, ldsb = (wave * 128 + 64) * 8;

    // LDS read offsets (kv-invariant): K frags per t, V frags per t,dt
    int koa[4], kob[4], vo[4][4];
#pragma unroll
    for (int t = 0; t < 4; t++) {
        const int krow = t * 16 + l16;
        koa[t] = (krow * 8 + (quad ^ (krow & 7))) * 8;
        kob[t] = (krow * 8 + ((4 + quad) ^ (krow & 7))) * 8;
#pragma unroll
        for (int dt = 0; dt < 4; dt++) {
            const int d = dt * 16 + l16;
            vo[t][dt] = (d * 8 + ((t * 2 + (quad >> 1)) ^ (d & 7))) * 8
                        + (quad & 1) * 4;
        }
    }

    const short4v ones4 = pk4(1.f, 1.f, 1.f, 1.f);

    floatx4 acc[2][4], accl[2];
#pragma unroll
    for (int m = 0; m < 2; m++) {
        accl[m] = zero4();
#pragma unroll
        for (int dt = 0; dt < 4; dt++) acc[m][dt] = zero4();
    }

    // prologue: stage tile 0 into buffer 0
    load_lds16(kga, &Ks[0][ldsa]);
    load_lds16(kgb, &Ks[0][ldsb]);
    load_lds16(vga, &Vs[0][ldsa]);
    load_lds16(vgb, &Vs[0][ldsb]);

    for (int it = 0; it < SEQ / 64; it++) {
        __syncthreads();  // drains staging issued last iter; readers done
        const int cur = it & 1;
        if (it + 1 < SEQ / 64) {
            const int nxt = cur ^ 1;
            const size_t kvn = (size_t)(it + 1) * 64;
            load_lds16(kga + kvn * DIM, &Ks[nxt][ldsa]);
            load_lds16(kgb + kvn * DIM, &Ks[nxt][ldsb]);
            load_lds16(vga + kvn, &Vs[nxt][ldsa]);
            load_lds16(vgb + kvn, &Vs[nxt][ldsb]);
        }

#pragma unroll
        for (int t = 0; t < 4; t++) {
            const bf16x8 kb0 = *(const bf16x8*)&Ks[cur][koa[t]];
            const bf16x8 kb1 = *(const bf16x8*)&Ks[cur][kob[t]];
            short4v vb[4];
#pragma unroll
            for (int dt = 0; dt < 4; dt++)
                vb[dt] = __builtin_bit_cast(short4v,
                    *(const bf16x4*)&Vs[cur][vo[t][dt]]);
#pragma unroll
            for (int m = 0; m < 2; m++) {
                floatx4 z = zero4();
                z = __builtin_amdgcn_mfma_f32_16x16x32_bf16(kb0, aq[m][0], z, 0, 0, 0);
                z = __builtin_amdgcn_mfma_f32_16x16x32_bf16(kb1, aq[m][1], z, 0, 0, 0);
                const short4v p = pk4(__builtin_amdgcn_exp2f(z[0]),
                                      __builtin_amdgcn_exp2f(z[1]),
                                      __builtin_amdgcn_exp2f(z[2]),
                                      __builtin_amdgcn_exp2f(z[3]));
#pragma unroll
                for (int dt = 0; dt < 4; dt++)
                    acc[m][dt] = __builtin_amdgcn_mfma_f32_16x16x16bf16_1k(
                        p, vb[dt], acc[m][dt], 0, 0, 0);
                accl[m] = __builtin_amdgcn_mfma_f32_16x16x16bf16_1k(
                    p, ones4, accl[m], 0, 0, 0);
            }
        }
    }

    // store: O rows q=qt+m*16+quad*4+i, cols dt*16+l16
#pragma unroll
    for (int m = 0; m < 2; m++) {
        float inv[4];
#pragma unroll
        for (int i = 0; i < 4; i++) inv[i] = 1.0f / accl[m][i];
        bf16* cp = Ctx + base_bh + (size_t)(qt + m * 16 + quad * 4) * DIM + l16;
#pragma unroll
        for (int i = 0; i < 4; i++)
#pragma unroll
            for (int dt = 0; dt < 4; dt++)
                cp[(size_t)i * DIM + dt * 16] = (bf16)(acc[m][dt][i] * inv[i]);
    }
}

// ---------------------------------------------------------------------------
extern "C" void kernel_launch(void* const* d_in, const int* in_sizes, int n_in,
                              void* d_out, int out_size, void* d_ws, size_t ws_size,
                              hipStream_t stream) {
    const float* X  = (const float*)d_in[0];
    const float* Wq = (const float*)d_in[1];
    const float* bq = (const float*)d_in[2];
    const float* Wk = (const float*)d_in[3];
    const float* bk = (const float*)d_in[4];
    const float* Wv = (const float*)d_in[5];
    const float* bv = (const float*)d_in[6];
    const float* Wo = (const float*)d_in[7];
    const float* bo = (const float*)d_in[8];
    float* out = (float*)d_out;

    const size_t MD = (size_t)MTOT * DIM;
    const size_t DD = (size_t)DIM * DIM;

    bf16* Xb  = (bf16*)d_ws;     // X bf16; reused as ctx after attention
    bf16* Qb  = Xb + MD;
    bf16* Kb  = Qb + MD;
    bf16* Vtb = Kb + MD;         // V transposed [B*H][DH][SEQ]
    bf16* Wqb = Vtb + MD;        // [Wq;Wk;Wv;Wo] rows contiguous
    bf16* Wob = Wqb + 3 * DD;
    if (ws_size < (MD * 4 + DD * 4) * sizeof(bf16)) return;

    cvt_all<<<(int)((MD + 4 * DD) / 4 / 256), 256, 0, stream>>>(
        X, Wq, Wk, Wv, Wo, Xb, Wqb);

    gemm_qkv<<<dim3(24, MTOT / 128), 256, 0, stream>>>(Xb, Wqb, bq, bk, bv,
                                                       Qb, Kb, Vtb);

    // 1024 blocks x 256 threads: XCD-swizzled 64 (b,h) x 16 q-blocks
    attn_kernel<<<NB * NH * (SEQ / 128), 256, 0, stream>>>(Qb, Kb, Vtb, Xb);

    gemm_out<<<dim3(8, MTOT / 128), 256, 0, stream>>>(Xb, Wob, bo, out);
}

// Round 11
// 270.508 us; speedup vs baseline: 1.2123x; 1.0900x over previous
//
#include <hip/hip_runtime.h>

// ---------------------------------------------------------------------------
// AttentionActPrune — full MHA forward. B=4, S=2048, H=16, DH=64, D=1024.
// fp32 in/out; threshold 2% of max|ref| -> bf16 MFMA compute.
// Pipeline: cvt_all -> merged QKV GEMM (Q pre-scaled by softmax const; V ->
// Vt[bh][d][s] transposed epilogue) -> flash-attn (kv-permuted K staging ->
// K=32 PV MFMAs, register P, XCD swizzle, ping-pong LDS) -> GEMM out.
// ---------------------------------------------------------------------------

typedef __bf16 bf16;
typedef __bf16 bf16x8 __attribute__((ext_vector_type(8)));
typedef __bf16 bf16x4 __attribute__((ext_vector_type(4)));
typedef float  floatx4 __attribute__((ext_vector_type(4)));

#define NB   4
#define SEQ  2048
#define NH   16
#define DH   64
#define DIM  1024
#define MTOT (NB * SEQ)   // 8192

#define CEXP 0.18033688f   // (1/sqrt(DH)) * log2(e), folded into Q

__device__ __forceinline__ floatx4 zero4() {
    floatx4 z; z[0] = 0.f; z[1] = 0.f; z[2] = 0.f; z[3] = 0.f; return z;
}

__device__ __forceinline__ void load_lds16(const bf16* g, bf16* l) {
    __builtin_amdgcn_global_load_lds(
        (__attribute__((address_space(1))) void*)g,
        (__attribute__((address_space(3))) void*)l,
        16, 0, 0);
}

// ---------------------------------------------------------------------------
// fp32 -> bf16 converts: X (MD elems) then [Wq;Wk;Wv;Wo] (4*DD) in one grid.
// ---------------------------------------------------------------------------
__global__ __launch_bounds__(256) void cvt_all(const float* __restrict__ X,
                                               const float* __restrict__ w0,
                                               const float* __restrict__ w1,
                                               const float* __restrict__ w2,
                                               const float* __restrict__ w3,
                                               bf16* __restrict__ Xb,
                                               bf16* __restrict__ Wb) {
    const size_t MD = (size_t)MTOT * DIM;
    const size_t DD = (size_t)DIM * DIM;   // 2^20
    size_t i = ((size_t)blockIdx.x * 256 + threadIdx.x) * 4;
    float4 f; bf16* dst;
    if (i < MD) {
        f = *(const float4*)(X + i);
        dst = Xb + i;
    } else {
        size_t off = i - MD;
        int w = (int)(off >> 20);
        size_t wi = off & (DD - 1);
        const float* ws = (w == 0) ? w0 : (w == 1) ? w1 : (w == 2) ? w2 : w3;
        f = *(const float4*)(ws + wi);
        dst = Wb + off;
    }
    bf16x4 o;
    o[0] = (bf16)f.x; o[1] = (bf16)f.y; o[2] = (bf16)f.z; o[3] = (bf16)f.w;
    *(bf16x4*)dst = o;
}

// ---------------------------------------------------------------------------
// Merged QKV GEMM. W = [Wq;Wk;Wv;Wo] rows contiguous. blockIdx.x: 0-7 Q,
// 8-15 K, 16-23 V(transposed epilogue). C[m][n]=sum_k A[m][k]W[n][k]+b[n].
// Q output (sel==0) additionally scaled by CEXP (softmax fold).
// ---------------------------------------------------------------------------
__global__ __launch_bounds__(256) void gemm_qkv(const bf16* __restrict__ A,
                                                const bf16* __restrict__ W,
                                                const float* __restrict__ bq,
                                                const float* __restrict__ bk,
                                                const float* __restrict__ bv,
                                                bf16* __restrict__ Qo,
                                                bf16* __restrict__ Ko,
                                                bf16* __restrict__ Vt) {
    __shared__ __align__(16) bf16 As[128 * 32];
    __shared__ __align__(16) bf16 Bs[128 * 32];
    __shared__ __align__(16) bf16 Ts[64 * 136];

    const int tid  = threadIdx.x;
    const int wave = tid >> 6, lane = tid & 63;
    const int quad = lane >> 4, l16 = lane & 15;
    const int sel = blockIdx.x >> 3;            // 0=Q 1=K 2=V
    const int nt  = blockIdx.x & 7;
    const int m0 = blockIdx.y * 128, n0 = nt * 128;
    const int wm = (wave & 1) * 64, wn = (wave >> 1) * 64;
    const bf16* Wsel = W + (size_t)(sel * DIM + n0) * DIM;
    const float* bias = (sel == 0) ? bq : (sel == 1) ? bk : bv;
    const float scale = (sel == 0) ? CEXP : 1.0f;

    floatx4 acc[4][4];
#pragma unroll
    for (int mi = 0; mi < 4; mi++)
#pragma unroll
        for (int ni = 0; ni < 4; ni++) acc[mi][ni] = zero4();

    for (int k0 = 0; k0 < DIM; k0 += 32) {
        __syncthreads();
#pragma unroll
        for (int i = 0; i < 2; i++) {
            const int cb = wave * 128 + i * 64;
            const int c  = cb + lane;
            const int row = c >> 2;
            const int kc  = (c & 3) * 8;
            load_lds16(A + (size_t)(m0 + row) * DIM + k0 + kc, &As[cb * 8]);
            load_lds16(Wsel + (size_t)row * DIM + k0 + kc, &Bs[cb * 8]);
        }
        __syncthreads();

        bf16x8 af[4], bfr[4];
#pragma unroll
        for (int mi = 0; mi < 4; mi++)
            af[mi] = *(const bf16x8*)&As[(wm + mi * 16 + l16) * 32 + quad * 8];
#pragma unroll
        for (int ni = 0; ni < 4; ni++)
            bfr[ni] = *(const bf16x8*)&Bs[(wn + ni * 16 + l16) * 32 + quad * 8];
#pragma unroll
        for (int mi = 0; mi < 4; mi++)
#pragma unroll
            for (int ni = 0; ni < 4; ni++)
                acc[mi][ni] = __builtin_amdgcn_mfma_f32_16x16x32_bf16(
                    af[mi], bfr[ni], acc[mi][ni], 0, 0, 0);
    }

    if (sel < 2) {
        bf16* C = (sel == 0) ? Qo : Ko;
#pragma unroll
        for (int mi = 0; mi < 4; mi++) {
            const int rbase = m0 + wm + mi * 16 + quad * 4;
#pragma unroll
            for (int ni = 0; ni < 4; ni++) {
                const int col = n0 + wn + ni * 16 + l16;
                const float bval = bias[col];
#pragma unroll
                for (int i = 0; i < 4; i++)
                    C[(size_t)(rbase + i) * DIM + col] =
                        (bf16)((acc[mi][ni][i] + bval) * scale);
            }
        }
    } else {
        // write Vt[(b*NH+h)][d][s], via LDS transpose (two 64-col halves)
        const int b  = blockIdx.y >> 4;
        const int s0 = (blockIdx.y & 15) * 128;
#pragma unroll
        for (int r = 0; r < 2; r++) {
            __syncthreads();
            if ((wave >> 1) == r) {
#pragma unroll
                for (int mi = 0; mi < 4; mi++) {
                    const int m_l = wm + mi * 16 + quad * 4;
#pragma unroll
                    for (int ni = 0; ni < 4; ni++) {
                        const int n_loc = ni * 16 + l16;
                        const float bval = bias[n0 + 64 * r + n_loc];
#pragma unroll
                        for (int i = 0; i < 4; i++)
                            Ts[n_loc * 136 + m_l + i] = (bf16)(acc[mi][ni][i] + bval);
                    }
                }
            }
            __syncthreads();
            const int hh = 2 * nt + r;
            bf16* obase = Vt + ((size_t)(b * NH + hh) * DH) * SEQ + s0;
#pragma unroll
            for (int p = 0; p < 4; p++) {
                const int chunk = p * 256 + tid;
                const int row = chunk >> 4, c0 = (chunk & 15) * 8;
                bf16x8 v = *(const bf16x8*)&Ts[row * 136 + c0];
                *(bf16x8*)(obase + (size_t)row * SEQ + c0) = v;
            }
        }
    }
}

// ---------------------------------------------------------------------------
// Out-projection GEMM (fp32 out), 128x128 tiles.
// ---------------------------------------------------------------------------
__global__ __launch_bounds__(256) void gemm_out(const bf16* __restrict__ A,
                                                const bf16* __restrict__ W,
                                                const float* __restrict__ bias,
                                                float* __restrict__ C) {
    __shared__ __align__(16) bf16 As[128 * 32];
    __shared__ __align__(16) bf16 Bs[128 * 32];

    const int tid  = threadIdx.x;
    const int wave = tid >> 6, lane = tid & 63;
    const int quad = lane >> 4, l16 = lane & 15;
    const int m0 = blockIdx.y * 128, n0 = blockIdx.x * 128;
    const int wm = (wave & 1) * 64, wn = (wave >> 1) * 64;

    floatx4 acc[4][4];
#pragma unroll
    for (int mi = 0; mi < 4; mi++)
#pragma unroll
        for (int ni = 0; ni < 4; ni++) acc[mi][ni] = zero4();

    for (int k0 = 0; k0 < DIM; k0 += 32) {
        __syncthreads();
#pragma unroll
        for (int i = 0; i < 2; i++) {
            const int cb = wave * 128 + i * 64;
            const int c  = cb + lane;
            const int row = c >> 2;
            const int kc  = (c & 3) * 8;
            load_lds16(A + (size_t)(m0 + row) * DIM + k0 + kc, &As[cb * 8]);
            load_lds16(W + (size_t)(n0 + row) * DIM + k0 + kc, &Bs[cb * 8]);
        }
        __syncthreads();

        bf16x8 af[4], bfr[4];
#pragma unroll
        for (int mi = 0; mi < 4; mi++)
            af[mi] = *(const bf16x8*)&As[(wm + mi * 16 + l16) * 32 + quad * 8];
#pragma unroll
        for (int ni = 0; ni < 4; ni++)
            bfr[ni] = *(const bf16x8*)&Bs[(wn + ni * 16 + l16) * 32 + quad * 8];
#pragma unroll
        for (int mi = 0; mi < 4; mi++)
#pragma unroll
            for (int ni = 0; ni < 4; ni++)
                acc[mi][ni] = __builtin_amdgcn_mfma_f32_16x16x32_bf16(
                    af[mi], bfr[ni], acc[mi][ni], 0, 0, 0);
    }

#pragma unroll
    for (int mi = 0; mi < 4; mi++) {
        const int rbase = m0 + wm + mi * 16 + quad * 4;
#pragma unroll
        for (int ni = 0; ni < 4; ni++) {
            const int col = n0 + wn + ni * 16 + l16;
            const float bval = bias[col];
#pragma unroll
            for (int i = 0; i < 4; i++)
                C[(size_t)(rbase + i) * DIM + col] = acc[mi][ni][i] + bval;
        }
    }
}

// ---------------------------------------------------------------------------
// Flash attention: 4-wave blocks = 128 q rows of one (b,h), 32 q/wave.
// XCD-swizzled grid (L2-resident K/V: round-10 FETCH 139->25 MB).
// NEW: K rows are staged PERMUTED within each 32-kv window:
//   LDS row r (r4 = r&15): kv = 32*(r>>5) + 8*(r4>>2) + 4*(r>=16 in window) + (r4&3)
// so the two 16-row S^T C-layouts concatenate into exactly the A-fragment
// (k=quad*8+j) of mfma_f32_16x16x32_bf16 -> PV runs at K=32:
// 28 MFMAs/tile (was 56), V frags are single b128 reads (was 2x b64).
// V staged in natural [d][s] order (B-frag k=quad*8+j = 8 contiguous s).
// Per-window batching: 4 K-frag reads -> 1 wait -> 4 QK -> 8 exp2 ->
// 4 V-frag b128 -> 10 PV/ones. Q pre-scaled by CEXP -> P = exp2(z).
// ---------------------------------------------------------------------------
__global__ __launch_bounds__(256, 4) void attn_kernel(const bf16* __restrict__ Q,
                                                      const bf16* __restrict__ K,
                                                      const bf16* __restrict__ Vt,
                                                      bf16* __restrict__ Ctx) {
    __shared__ __align__(16) bf16 Ks[2][64 * 64];  // swizzled, kv-permuted
    __shared__ __align__(16) bf16 Vs[2][64 * 64];  // swizzled, natural order

    const int tid  = threadIdx.x;
    const int wave = tid >> 6, lane = tid & 63;
    const int quad = lane >> 4, l16 = lane & 15;
    // XCD-aware swizzle (1024 blocks, 8 XCDs)
    const int xcd = blockIdx.x & 7;
    const int j   = blockIdx.x >> 3;        // 0..127
    const int bh  = xcd * 8 + (j >> 4);     // b*NH + h
    const int qb  = j & 15;                 // 128-row q block
    const int b   = bh >> 4, h = bh & 15;

    const size_t base_bh = (size_t)b * SEQ * DIM + (size_t)h * DH;
    const size_t base_v  = (size_t)bh * DH * SEQ;
    const int qt = qb * 128 + wave * 32;    // wave's 32 q rows

    // Q frags (B-operand of swapped QK MFMA): 2 m-subtiles x 2 d-halves
    bf16x8 aq[2][2];
#pragma unroll
    for (int m = 0; m < 2; m++) {
        const bf16* qp = Q + base_bh + (size_t)(qt + m * 16 + l16) * DIM + quad * 8;
        aq[m][0] = *(const bf16x8*)qp;
        aq[m][1] = *(const bf16x8*)(qp + 32);
    }

    // staging addresses (kv-invariant): chunk ids sc, sc+64 per array
    const int sc = wave * 128 + lane;
    int srow[2], scol[2];
    srow[0] = sc >> 3;        srow[1] = (sc + 64) >> 3;
    scol[0] = (sc & 7) ^ (srow[0] & 7);
    scol[1] = ((sc + 64) & 7) ^ (srow[1] & 7);
    // K permuted kv offset for a physical row r
    auto kvloc = [](int r) {
        const int w = r >> 5, rw = r & 31, r4 = rw & 15;
        return w * 32 + ((rw >> 4) << 2) + ((r4 >> 2) << 3) + (r4 & 3);
    };
    const bf16* kga = K + base_bh + (size_t)kvloc(srow[0]) * DIM + scol[0] * 8;
    const bf16* kgb = K + base_bh + (size_t)kvloc(srow[1]) * DIM + scol[1] * 8;
    const bf16* vga = Vt + base_v + (size_t)srow[0] * SEQ + scol[0] * 8;
    const bf16* vgb = Vt + base_v + (size_t)srow[1] * SEQ + scol[1] * 8;
    const int ldsa = (wave * 128) * 8, ldsb = (wave * 128 + 64) * 8;

    // LDS read offsets (kv-invariant): K frags per group g, V per (w,dt)
    int koa[4], kob[4], vo[2][4];
#pragma unroll
    for (int g = 0; g < 4; g++) {
        const int krow = g * 16 + l16;
        koa[g] = (krow * 8 + (quad ^ (krow & 7))) * 8;
        kob[g] = (krow * 8 + ((4 + quad) ^ (krow & 7))) * 8;
    }
#pragma unroll
    for (int w = 0; w < 2; w++)
#pragma unroll
        for (int dt = 0; dt < 4; dt++) {
            const int d = dt * 16 + l16;
            vo[w][dt] = d * 64 + ((4 * w + quad) ^ (d & 7)) * 8;
        }

    bf16x8 ones8;
#pragma unroll
    for (int i = 0; i < 8; i++) ones8[i] = (bf16)1.0f;

    floatx4 acc[2][4], accl[2];
#pragma unroll
    for (int m = 0; m < 2; m++) {
        accl[m] = zero4();
#pragma unroll
        for (int dt = 0; dt < 4; dt++) acc[m][dt] = zero4();
    }

    // prologue: stage tile 0 into buffer 0
    load_lds16(kga, &Ks[0][ldsa]);
    load_lds16(kgb, &Ks[0][ldsb]);
    load_lds16(vga, &Vs[0][ldsa]);
    load_lds16(vgb, &Vs[0][ldsb]);

    for (int it = 0; it < SEQ / 64; it++) {
        __syncthreads();  // drains staging issued last iter; readers done
        const int cur = it & 1;
        if (it + 1 < SEQ / 64) {
            const int nxt = cur ^ 1;
            const size_t kvn = (size_t)(it + 1) * 64;
            load_lds16(kga + kvn * DIM, &Ks[nxt][ldsa]);
            load_lds16(kgb + kvn * DIM, &Ks[nxt][ldsb]);
            load_lds16(vga + kvn, &Vs[nxt][ldsa]);
            load_lds16(vgb + kvn, &Vs[nxt][ldsb]);
        }

#pragma unroll
        for (int w = 0; w < 2; w++) {
            // K frags for groups 2w (even: k=8q..8q+3), 2w+1 (odd: 8q+4..7)
            const bf16x8 ke0 = *(const bf16x8*)&Ks[cur][koa[2 * w]];
            const bf16x8 ke1 = *(const bf16x8*)&Ks[cur][kob[2 * w]];
            const bf16x8 ko0 = *(const bf16x8*)&Ks[cur][koa[2 * w + 1]];
            const bf16x8 ko1 = *(const bf16x8*)&Ks[cur][kob[2 * w + 1]];
            bf16x8 pw[2];
#pragma unroll
            for (int m = 0; m < 2; m++) {
                floatx4 sa = zero4(), sb = zero4();
                sa = __builtin_amdgcn_mfma_f32_16x16x32_bf16(ke0, aq[m][0], sa, 0, 0, 0);
                sa = __builtin_amdgcn_mfma_f32_16x16x32_bf16(ke1, aq[m][1], sa, 0, 0, 0);
                sb = __builtin_amdgcn_mfma_f32_16x16x32_bf16(ko0, aq[m][0], sb, 0, 0, 0);
                sb = __builtin_amdgcn_mfma_f32_16x16x32_bf16(ko1, aq[m][1], sb, 0, 0, 0);
                bf16x8 p;
#pragma unroll
                for (int i = 0; i < 4; i++) {
                    p[i]     = (bf16)__builtin_amdgcn_exp2f(sa[i]);
                    p[4 + i] = (bf16)__builtin_amdgcn_exp2f(sb[i]);
                }
                pw[m] = p;
            }
            // V frags: b128, natural kv order
            bf16x8 vf[4];
#pragma unroll
            for (int dt = 0; dt < 4; dt++)
                vf[dt] = *(const bf16x8*)&Vs[cur][vo[w][dt]];
#pragma unroll
            for (int m = 0; m < 2; m++) {
#pragma unroll
                for (int dt = 0; dt < 4; dt++)
                    acc[m][dt] = __builtin_amdgcn_mfma_f32_16x16x32_bf16(
                        pw[m], vf[dt], acc[m][dt], 0, 0, 0);
                accl[m] = __builtin_amdgcn_mfma_f32_16x16x32_bf16(
                    pw[m], ones8, accl[m], 0, 0, 0);
            }
        }
    }

    // store: O rows q=qt+m*16+quad*4+i, cols dt*16+l16
#pragma unroll
    for (int m = 0; m < 2; m++) {
        float inv[4];
#pragma unroll
        for (int i = 0; i < 4; i++) inv[i] = 1.0f / accl[m][i];
        bf16* cp = Ctx + base_bh + (size_t)(qt + m * 16 + quad * 4) * DIM + l16;
#pragma unroll
        for (int i = 0; i < 4; i++)
#pragma unroll
            for (int dt = 0; dt < 4; dt++)
                cp[(size_t)i * DIM + dt * 16] = (bf16)(acc[m][dt][i] * inv[i]);
    }
}

// ---------------------------------------------------------------------------
extern "C" void kernel_launch(void* const* d_in, const int* in_sizes, int n_in,
                              void* d_out, int out_size, void* d_ws, size_t ws_size,
                              hipStream_t stream) {
    const float* X  = (const float*)d_in[0];
    const float* Wq = (const float*)d_in[1];
    const float* bq = (const float*)d_in[2];
    const float* Wk = (const float*)d_in[3];
    const float* bk = (const float*)d_in[4];
    const float* Wv = (const float*)d_in[5];
    const float* bv = (const float*)d_in[6];
    const float* Wo = (const float*)d_in[7];
    const float* bo = (const float*)d_in[8];
    float* out = (float*)d_out;

    const size_t MD = (size_t)MTOT * DIM;
    const size_t DD = (size_t)DIM * DIM;

    bf16* Xb  = (bf16*)d_ws;     // X bf16; reused as ctx after attention
    bf16* Qb  = Xb + MD;
    bf16* Kb  = Qb + MD;
    bf16* Vtb = Kb + MD;         // V transposed [B*H][DH][SEQ]
    bf16* Wqb = Vtb + MD;        // [Wq;Wk;Wv;Wo] rows contiguous
    bf16* Wob = Wqb + 3 * DD;
    if (ws_size < (MD * 4 + DD * 4) * sizeof(bf16)) return;

    cvt_all<<<(int)((MD + 4 * DD) / 4 / 256), 256, 0, stream>>>(
        X, Wq, Wk, Wv, Wo, Xb, Wqb);

    gemm_qkv<<<dim3(24, MTOT / 128), 256, 0, stream>>>(Xb, Wqb, bq, bk, bv,
                                                       Qb, Kb, Vtb);

    // 1024 blocks x 256 threads: XCD-swizzled 64 (b,h) x 16 q-blocks
    attn_kernel<<<NB * NH * (SEQ / 128), 256, 0, stream>>>(Qb, Kb, Vtb, Xb);

    gemm_out<<<dim3(8, MTOT / 128), 256, 0, stream>>>(Xb, Wob, bo, out);
}